// Round 8
// baseline (4079.897 us; speedup 1.0000x reference)
//
#include <hip/hip_runtime.h>
#include <cstddef>
#include <cstdint>

// Problem constants (from reference)
#define SEQB   8
#define SEQL   2048
#define DMODEL 1024
#define DINNER 2048
#define DSTATE 16
#define NC     32            // scan chunks along t
#define TC     64            // SEQL/NC
#define TT     8             // scan LDS tile rows (t per stage)

typedef __attribute__((ext_vector_type(4))) float f32x4;
typedef __attribute__((ext_vector_type(8))) short bf16x8;
typedef unsigned int u32;
typedef const __attribute__((address_space(1))) u32* gas_ptr;
typedef __attribute__((address_space(3))) u32* las_ptr;

__device__ __forceinline__ void gld16(const void* g, void* l){
  __builtin_amdgcn_global_load_lds((gas_ptr)g, (las_ptr)l, 16, 0, 0);
}

__device__ __forceinline__ float siluf(float x){ return x / (1.f + __expf(-x)); }
__device__ __forceinline__ float softplusf(float x){ return (x > 20.f) ? x : log1pf(__expf(x)); }

// RNE fp32 -> bf16 bits
__device__ __forceinline__ unsigned short f2bf_rne(float f){
  unsigned int u = __float_as_uint(f);
  u += 0x7FFFu + ((u>>16)&1u);
  return (unsigned short)(u>>16);
}
__device__ __forceinline__ void split_bf(float f, unsigned short& h, unsigned short& l){
  unsigned short hs = f2bf_rne(f);
  float hf = __uint_as_float(((unsigned int)hs)<<16);
  h = hs;
  l = f2bf_rne(f - hf);
}

// Convert 8 consecutive fp32 at PSRC into hi/lo bf16x8 and store (generic ptr).
#define CV8(PH, PL, PSRC) { \
  const float4* _p4 = (const float4*)(PSRC); \
  float4 _a = _p4[0], _b = _p4[1]; \
  bf16x8 _H, _L; unsigned short _h,_l; \
  split_bf(_a.x,_h,_l); _H[0]=(short)_h; _L[0]=(short)_l; \
  split_bf(_a.y,_h,_l); _H[1]=(short)_h; _L[1]=(short)_l; \
  split_bf(_a.z,_h,_l); _H[2]=(short)_h; _L[2]=(short)_l; \
  split_bf(_a.w,_h,_l); _H[3]=(short)_h; _L[3]=(short)_l; \
  split_bf(_b.x,_h,_l); _H[4]=(short)_h; _L[4]=(short)_l; \
  split_bf(_b.y,_h,_l); _H[5]=(short)_h; _L[5]=(short)_l; \
  split_bf(_b.z,_h,_l); _H[6]=(short)_h; _L[6]=(short)_l; \
  split_bf(_b.w,_h,_l); _H[7]=(short)_h; _L[7]=(short)_l; \
  *(bf16x8*)(PH) = _H; *(bf16x8*)(PL) = _L; }

// ---------------------------------------------------------------------------
// Weight pre-split PAIR {h|l}: src [R][K] fp32 -> dst [R][2K] bf16.
// ---------------------------------------------------------------------------
__global__ __launch_bounds__(256)
void wsplit2(const float* __restrict__ src, unsigned short* __restrict__ dst,
             int K, int k4shift)
{
  int idx = blockIdx.x*256 + threadIdx.x;
  int r  = idx >> k4shift;
  int c4 = idx & ((1<<k4shift)-1);
  float4 v = ((const float4*)src)[idx];
  unsigned short h,l; short4 h4, l4;
  split_bf(v.x,h,l); h4.x=(short)h; l4.x=(short)l;
  split_bf(v.y,h,l); h4.y=(short)h; l4.y=(short)l;
  split_bf(v.z,h,l); h4.z=(short)h; l4.z=(short)l;
  split_bf(v.w,h,l); h4.w=(short)h; l4.w=(short)l;
  size_t ro = (size_t)r*2*K;
  *(short4*)&dst[ro + (c4<<2)]     = h4;
  *(short4*)&dst[ro + K + (c4<<2)] = l4;
}

// ---------------------------------------------------------------------------
// out_proj weight split, TWO INTERLEAVED VARIANTS per layer:
// var0[r][2d,2d+1] = (h',h')   var1[r][2d,2d+1] = (l',0)
// dst layout: [layer][variant][1024][4096] ushort.
// Paired with A packed (h,l) per d: pass0 -> hh+lh, pass1 -> hl.
// ---------------------------------------------------------------------------
__global__ __launch_bounds__(256)
void wsplit_ov(const float* __restrict__ src, unsigned short* __restrict__ dst)
{
  int idx = blockIdx.x*256 + threadIdx.x;    // per 4 elems; total 2*1024*2048/4
  int r  = idx >> 9;                         // 0..2047 (layer*1024 + rr)
  int c4 = idx & 511;
  int layer = r >> 10, rr = r & 1023;
  float4 v = ((const float4*)src)[idx];
  unsigned short h[4], l[4];
  split_bf(v.x,h[0],l[0]); split_bf(v.y,h[1],l[1]);
  split_bf(v.z,h[2],l[2]); split_bf(v.w,h[3],l[3]);
  size_t base = (size_t)layer*2*1024*4096 + (size_t)rr*4096 + ((size_t)c4<<3);
  short4 a,b;
  a.x=(short)h[0]; a.y=(short)h[0]; a.z=(short)h[1]; a.w=(short)h[1];
  b.x=(short)h[2]; b.y=(short)h[2]; b.z=(short)h[3]; b.w=(short)h[3];
  *(short4*)&dst[base]   = a;
  *(short4*)&dst[base+4] = b;
  size_t base1 = base + (size_t)1024*4096;
  a.x=(short)l[0]; a.y=0; a.z=(short)l[1]; a.w=0;
  b.x=(short)l[2]; b.y=0; b.z=(short)l[3]; b.w=0;
  *(short4*)&dst[base1]   = a;
  *(short4*)&dst[base1+4] = b;
}

// ---------------------------------------------------------------------------
// LayerNorm (+ optional residual) fused with PAIR split {h|l}:
// writes Hs [row][2048] bf16 (cols 0..1023 = h, 1024..2047 = l).
// ---------------------------------------------------------------------------
__global__ __launch_bounds__(256)
void ln_split2(const float* __restrict__ a, const float* __restrict__ res,
               const float* __restrict__ w, const float* __restrict__ bias,
               unsigned short* __restrict__ Hs)
{
  int row = blockIdx.x;
  size_t off = (size_t)row * DMODEL;
  float4 v = ((const float4*)(a + off))[threadIdx.x];
  if (res){
    float4 u = ((const float4*)(res + off))[threadIdx.x];
    v.x += u.x; v.y += u.y; v.z += u.z; v.w += u.w;
  }
  float s  = v.x + v.y + v.z + v.w;
  float s2 = fmaf(v.x,v.x, fmaf(v.y,v.y, fmaf(v.z,v.z, v.w*v.w)));
  #pragma unroll
  for (int o=32;o>0;o>>=1){ s += __shfl_down(s,o,64); s2 += __shfl_down(s2,o,64); }
  __shared__ float red[8];
  int lane = threadIdx.x & 63, wid = threadIdx.x >> 6;
  if (lane==0){ red[wid]=s; red[4+wid]=s2; }
  __syncthreads();
  s  = red[0]+red[1]+red[2]+red[3];
  s2 = red[4]+red[5]+red[6]+red[7];
  float mu  = s * (1.f/DMODEL);
  float var = s2 * (1.f/DMODEL) - mu*mu;
  float rstd = rsqrtf(var + 1e-5f);
  float4 wv = ((const float4*)w)[threadIdx.x];
  float4 bv = ((const float4*)bias)[threadIdx.x];
  float4 o4;
  o4.x = (v.x-mu)*rstd*wv.x + bv.x;
  o4.y = (v.y-mu)*rstd*wv.y + bv.y;
  o4.z = (v.z-mu)*rstd*wv.z + bv.z;
  o4.w = (v.w-mu)*rstd*wv.w + bv.w;
  unsigned short h,l; short4 h4, l4;
  split_bf(o4.x,h,l); h4.x=(short)h; l4.x=(short)l;
  split_bf(o4.y,h,l); h4.y=(short)h; l4.y=(short)l;
  split_bf(o4.z,h,l); h4.z=(short)h; l4.z=(short)l;
  split_bf(o4.w,h,l); h4.w=(short)h; l4.w=(short)l;
  size_t ro = (size_t)row*2048;
  int c = threadIdx.x<<2;
  *(short4*)&Hs[ro + c]        = h4;
  *(short4*)&Hs[ro + 1024 + c] = l4;
}

// ---------------------------------------------------------------------------
// in_proj GEMM, pair-remap split-fp32: C = A*B^T with A,B stored as {h|l}
// pairs (K=1024 each half). Virtual K-loop of 3x1024 realizes hh+hl+lh.
// 128x128 tile, BK=32, gld16 staging, both-sides XOR swizzle.
// Epilogue splits cols: n<2048 -> XI (xi), else -> ZB (z). M,N mult of 128.
// ---------------------------------------------------------------------------
__global__ __launch_bounds__(256)
void mgemm_in(const unsigned short* __restrict__ A,   // [M][2048] {h|l}
              const unsigned short* __restrict__ B,   // [4096][2048] {h|l}
              float* __restrict__ XI, float* __restrict__ ZB)
{
  __shared__ __align__(16) unsigned short As[128*32];
  __shared__ __align__(16) unsigned short Bs[128*32];
  const int t = threadIdx.x;
  const int mbase = blockIdx.y << 7, nbase = blockIdx.x << 7;
  const int lane = t & 63, w = t >> 6;
  const int wr = w >> 1, wc = w & 1;
  const int l16 = lane & 15, kq = lane >> 4;

  const int srow = t >> 2, sl = t & 3;
  const int co0 = ((sl ^ ((srow>>1)&3)) << 3);
  const int co1 = ((sl ^ (((srow+64)>>1)&3)) << 3);
  const unsigned short* pa0 = A + (size_t)(mbase+srow)*2048 + co0;
  const unsigned short* pa1 = A + (size_t)(mbase+srow+64)*2048 + co1;
  const unsigned short* pb0 = B + (size_t)(nbase+srow)*2048 + co0;
  const unsigned short* pb1 = B + (size_t)(nbase+srow+64)*2048 + co1;
  unsigned short* da0 = &As[srow*32 + sl*8];
  unsigned short* da1 = &As[(srow+64)*32 + sl*8];
  unsigned short* db0 = &Bs[srow*32 + sl*8];
  unsigned short* db1 = &Bs[(srow+64)*32 + sl*8];

  f32x4 acc[4][4];
  #pragma unroll
  for (int i=0;i<4;i++)
    #pragma unroll
    for (int j=0;j<4;j++) acc[i][j] = (f32x4){0.f,0.f,0.f,0.f};

  #pragma unroll
  for (int kb=0; kb<3; kb++){
    const int ao = (kb==2) ? 1024 : 0;   // A: {h,h,l}
    const int bo = (kb==1) ? 1024 : 0;   // B: {h,l,h}
    for (int kk=0; kk<1024; kk+=32){
      gld16(pa0 + ao + kk, da0);
      gld16(pa1 + ao + kk, da1);
      gld16(pb0 + bo + kk, db0);
      gld16(pb1 + bo + kk, db1);
      __syncthreads();
      bf16x8 af[4];
      #pragma unroll
      for (int mf=0; mf<4; mf++){
        int ra = wr*64 + mf*16 + l16;
        af[mf] = *(const bf16x8*)&As[ra*32 + ((kq ^ ((ra>>1)&3))<<3)];
      }
      #pragma unroll
      for (int nf=0; nf<4; nf++){
        int rb = wc*64 + nf*16 + l16;
        bf16x8 bfr = *(const bf16x8*)&Bs[rb*32 + ((kq ^ ((rb>>1)&3))<<3)];
        #pragma unroll
        for (int mf=0; mf<4; mf++)
          acc[mf][nf] = __builtin_amdgcn_mfma_f32_16x16x32_bf16(af[mf], bfr, acc[mf][nf], 0,0,0);
      }
      __syncthreads();
    }
  }

  float* Cd = (nbase < 2048) ? XI : ZB;
  const int cb = (nbase < 2048) ? nbase : (nbase - 2048);
  #pragma unroll
  for (int mf=0; mf<4; mf++){
    int r0 = mbase + wr*64 + mf*16 + kq*4;
    #pragma unroll
    for (int nf=0; nf<4; nf++){
      int c = cb + wc*64 + nf*16 + l16;
      #pragma unroll
      for (int r=0;r<4;r++)
        Cd[(size_t)(r0+r)*2048 + c] = acc[mf][nf][r];
    }
  }
}

// ---------------------------------------------------------------------------
// out_proj GEMM: A = gated-y PACKED (h,l) u32 per d ([M][4096] ushort view),
// B = two interleaved variants ([2][1024][4096]).  Two K=4096 passes:
// pass0 (var0 = h',h') -> hh+lh ; pass1 (var1 = l',0) -> hl.
// Same 128x128/BK=32/gld16/XOR-swizzle structure as mgemm_in.
// ---------------------------------------------------------------------------
__global__ __launch_bounds__(256)
void mgemm_out(const unsigned short* __restrict__ A,   // [M][4096] packed
               const unsigned short* __restrict__ B,   // [2][1024][4096]
               float* __restrict__ C)                  // [M][1024]
{
  __shared__ __align__(16) unsigned short As[128*32];
  __shared__ __align__(16) unsigned short Bs[128*32];
  const int t = threadIdx.x;
  const int mbase = blockIdx.y << 7, nbase = blockIdx.x << 7;
  const int lane = t & 63, w = t >> 6;
  const int wr = w >> 1, wc = w & 1;
  const int l16 = lane & 15, kq = lane >> 4;

  const int srow = t >> 2, sl = t & 3;
  const int co0 = ((sl ^ ((srow>>1)&3)) << 3);
  const int co1 = ((sl ^ (((srow+64)>>1)&3)) << 3);
  const unsigned short* pa0 = A + (size_t)(mbase+srow)*4096 + co0;
  const unsigned short* pa1 = A + (size_t)(mbase+srow+64)*4096 + co1;
  const unsigned short* pb0 = B + (size_t)(nbase+srow)*4096 + co0;
  const unsigned short* pb1 = B + (size_t)(nbase+srow+64)*4096 + co1;
  unsigned short* da0 = &As[srow*32 + sl*8];
  unsigned short* da1 = &As[(srow+64)*32 + sl*8];
  unsigned short* db0 = &Bs[srow*32 + sl*8];
  unsigned short* db1 = &Bs[(srow+64)*32 + sl*8];

  f32x4 acc[4][4];
  #pragma unroll
  for (int i=0;i<4;i++)
    #pragma unroll
    for (int j=0;j<4;j++) acc[i][j] = (f32x4){0.f,0.f,0.f,0.f};

  #pragma unroll
  for (int kb=0; kb<2; kb++){
    const size_t bvo = (size_t)kb*1024*4096;
    for (int kk=0; kk<4096; kk+=32){
      gld16(pa0 + kk, da0);
      gld16(pa1 + kk, da1);
      gld16(pb0 + bvo + kk, db0);
      gld16(pb1 + bvo + kk, db1);
      __syncthreads();
      bf16x8 af[4];
      #pragma unroll
      for (int mf=0; mf<4; mf++){
        int ra = wr*64 + mf*16 + l16;
        af[mf] = *(const bf16x8*)&As[ra*32 + ((kq ^ ((ra>>1)&3))<<3)];
      }
      #pragma unroll
      for (int nf=0; nf<4; nf++){
        int rb = wc*64 + nf*16 + l16;
        bf16x8 bfr = *(const bf16x8*)&Bs[rb*32 + ((kq ^ ((rb>>1)&3))<<3)];
        #pragma unroll
        for (int mf=0; mf<4; mf++)
          acc[mf][nf] = __builtin_amdgcn_mfma_f32_16x16x32_bf16(af[mf], bfr, acc[mf][nf], 0,0,0);
      }
      __syncthreads();
    }
  }

  #pragma unroll
  for (int mf=0; mf<4; mf++){
    int r0 = mbase + wr*64 + mf*16 + kq*4;
    #pragma unroll
    for (int nf=0; nf<4; nf++){
      int c = nbase + wc*64 + nf*16 + l16;
      #pragma unroll
      for (int r=0;r<4;r++)
        C[(size_t)(r0+r)*1024 + c] = acc[mf][nf][r];
    }
  }
}

// ---------------------------------------------------------------------------
// x_proj MFMA: XD[m,0..95] = sum_k U[m,k]*W[n,k].  W pre-split {h|l} pair
// ([96][4096], gld16-staged, XOR swizzle); A (U) converted in-kernel by
// wave 0 only. 32-row tiles, 3-term split accumulate.
// ---------------------------------------------------------------------------
__global__ __launch_bounds__(256)
void xproj_mfma(const float* __restrict__ A,            // [M][2048] fp32 (U)
                const unsigned short* __restrict__ W2,  // [96][4096] {h|l}
                float* __restrict__ XD)                 // [M][96]
{
  __shared__ __align__(16) unsigned short Ah[32][40], Al[32][40];
  __shared__ __align__(16) unsigned short Bh[96*32], Bl[96*32];
  const int t = threadIdx.x;
  const int mbase = blockIdx.x << 5;
  const int lane = t & 63, w = t >> 6;
  const int mf = w & 1, nc0 = (w >> 1) * 48;
  const int l16 = lane & 15, kq = lane >> 4;

  // A conversion coords (wave 0): 32 rows x 32 cols per k-step
  const int ar = t >> 1, ahalf = (t & 1) << 4;
  const float* psA = A + (size_t)(mbase + ar)*2048 + ahalf;

  // B staging coords (waves 1..3): chunks tb and tb+192 (rows r0, r0+48)
  const int tb = t - 64;
  const int r0 = tb >> 2, sl0 = tb & 3;
  const int r1 = r0 + 48;
  const int c0 = ((sl0 ^ ((r0>>1)&3)) << 3);
  const int c1 = ((sl0 ^ ((r1>>1)&3)) << 3);
  const unsigned short* pb0 = W2 + (size_t)r0*4096 + c0;
  const unsigned short* pb1 = W2 + (size_t)r1*4096 + c1;
  unsigned short* dbh0 = &Bh[tb*8];
  unsigned short* dbh1 = &Bh[(tb+192)*8];
  unsigned short* dbl0 = &Bl[tb*8];
  unsigned short* dbl1 = &Bl[(tb+192)*8];

  f32x4 acc[3];
  #pragma unroll
  for (int j=0;j<3;j++) acc[j] = (f32x4){0.f,0.f,0.f,0.f};

  for (int k0=0; k0<2048; k0+=32){
    if (w == 0){
      CV8(&Ah[ar][ahalf],   &Al[ar][ahalf],   psA + k0);
      CV8(&Ah[ar][ahalf+8], &Al[ar][ahalf+8], psA + k0 + 8);
    } else {
      gld16(pb0 + k0,        dbh0);
      gld16(pb1 + k0,        dbh1);
      gld16(pb0 + 2048 + k0, dbl0);
      gld16(pb1 + 2048 + k0, dbl1);
    }
    __syncthreads();
    bf16x8 ah = *(const bf16x8*)&Ah[mf*16 + l16][kq*8];
    bf16x8 av = *(const bf16x8*)&Al[mf*16 + l16][kq*8];
    #pragma unroll
    for (int nf=0; nf<3; nf++){
      int br = nc0 + nf*16 + l16;
      int bo = br*32 + ((kq ^ ((br>>1)&3))<<3);
      bf16x8 bh = *(const bf16x8*)&Bh[bo];
      bf16x8 bl = *(const bf16x8*)&Bl[bo];
      acc[nf] = __builtin_amdgcn_mfma_f32_16x16x32_bf16(ah, bh, acc[nf], 0,0,0);
      acc[nf] = __builtin_amdgcn_mfma_f32_16x16x32_bf16(ah, bl, acc[nf], 0,0,0);
      acc[nf] = __builtin_amdgcn_mfma_f32_16x16x32_bf16(av, bh, acc[nf], 0,0,0);
    }
    __syncthreads();
  }
  #pragma unroll
  for (int nf=0; nf<3; nf++){
    int c = nc0 + nf*16 + l16;
    int r0s = mbase + mf*16 + kq*4;
    #pragma unroll
    for (int r=0;r<4;r++)
      XD[(size_t)(r0s+r)*96 + c] = acc[nf][r];
  }
}

// ---------------------------------------------------------------------------
// fp32 NT GEMM (dt_proj, K=64): C = softplus(A*B^T + ebias[n]).  N mult 128.
// ---------------------------------------------------------------------------
__global__ __launch_bounds__(256)
void gemm_dt(const float* __restrict__ A, int lda,
             const float* __restrict__ B, int ldb,
             float* __restrict__ C, int ldc,
             int K, const float* __restrict__ ebias)
{
  __shared__ float As[16][132];
  __shared__ float Bs[16][132];
  int tid = threadIdx.x;
  int tx = tid & 15, ty = tid >> 4;
  int mbase = blockIdx.y << 7;
  int nbase = blockIdx.x << 7;
  float acc[8][8];
  #pragma unroll
  for (int i=0;i<8;i++)
    #pragma unroll
    for (int j=0;j<8;j++) acc[i][j]=0.f;

  for (int k0=0;k0<K;k0+=16){
    #pragma unroll
    for (int it=0; it<2; it++){
      int idx = tid + (it<<8);
      int row = idx >> 2;
      int kq  = (idx & 3) << 2;
      float4 va = *(const float4*)(A + (size_t)(mbase+row)*lda + k0 + kq);
      As[kq+0][row]=va.x; As[kq+1][row]=va.y; As[kq+2][row]=va.z; As[kq+3][row]=va.w;
      float4 vb = *(const float4*)(B + (size_t)(nbase+row)*ldb + k0 + kq);
      Bs[kq+0][row]=vb.x; Bs[kq+1][row]=vb.y; Bs[kq+2][row]=vb.z; Bs[kq+3][row]=vb.w;
    }
    __syncthreads();
    #pragma unroll
    for (int k=0;k<16;k++){
      float a[8], bb[8];
      *(float4*)&a[0]  = *(const float4*)&As[k][ty<<2];
      *(float4*)&a[4]  = *(const float4*)&As[k][64+(ty<<2)];
      *(float4*)&bb[0] = *(const float4*)&Bs[k][tx<<2];
      *(float4*)&bb[4] = *(const float4*)&Bs[k][64+(tx<<2)];
      #pragma unroll
      for (int i=0;i<8;i++)
        #pragma unroll
        for (int j=0;j<8;j++)
          acc[i][j] = fmaf(a[i], bb[j], acc[i][j]);
    }
    __syncthreads();
  }

  int n0 = nbase + (tx<<2);
  int n1 = n0 + 64;
  float4 eb0 = *(const float4*)(ebias + n0);
  float4 eb1 = *(const float4*)(ebias + n1);
  #pragma unroll
  for (int i=0;i<8;i++){
    int mrow = mbase + ((i<4) ? ((ty<<2)+i) : (64 + (ty<<2) + (i-4)));
    float4 c0 = make_float4(acc[i][0],acc[i][1],acc[i][2],acc[i][3]);
    float4 c1 = make_float4(acc[i][4],acc[i][5],acc[i][6],acc[i][7]);
    c0.x = softplusf(c0.x+eb0.x); c0.y = softplusf(c0.y+eb0.y);
    c0.z = softplusf(c0.z+eb0.z); c0.w = softplusf(c0.w+eb0.w);
    c1.x = softplusf(c1.x+eb1.x); c1.y = softplusf(c1.y+eb1.y);
    c1.z = softplusf(c1.z+eb1.z); c1.w = softplusf(c1.w+eb1.w);
    *(float4*)(C + (size_t)mrow*ldc + n0) = c0;
    *(float4*)(C + (size_t)mrow*ldc + n1) = c1;
  }
}

// ---------------------------------------------------------------------------
// Causal depthwise conv (k=4) + bias + SiLU: XI (stride 2048) -> U.
// ---------------------------------------------------------------------------
__global__ __launch_bounds__(256)
void conv_silu_kernel(const float* __restrict__ xi, const float* __restrict__ cw,
                      const float* __restrict__ cb, float* __restrict__ xc)
{
  int idx = blockIdx.x*256 + threadIdx.x;
  int d = idx & (DINNER-1);
  int g = idx >> 11;
  int t0 = (g & 511) << 2;
  int b = g >> 9;
  float4 w4 = *(const float4*)(cw + d*4);
  float bias = cb[d];
  const float* base = xi + (size_t)b*SEQL*DINNER + d;
  float v[7];
  #pragma unroll
  for (int j=0;j<7;j++){
    int t = t0-3+j;
    v[j] = (t>=0) ? base[(size_t)t*DINNER] : 0.f;
  }
  float* outp = xc + ((size_t)b*SEQL + t0)*DINNER + d;
  #pragma unroll
  for (int j=0;j<4;j++){
    float y = fmaf(v[j+3], w4.w, fmaf(v[j+2], w4.z, fmaf(v[j+1], w4.y, fmaf(v[j], w4.x, bias))));
    outp[(size_t)j*DINNER] = siluf(y);
  }
}

// ---------------------------------------------------------------------------
// Chunked selective scan, LDS-tiled + fully-unrolled (static B/C indexing).
// PASS 1: local scan from h=0; write h_final -> hfin, sum(dt) -> sumdt.
// PASS 3: local scan from hfin; y = (C.h + u*D)*silu(z); SPLIT to bf16 pair
//         and write PACKED u32 (h | l<<16) in place over dt bytes -> the
//         out_proj A-operand layout.  Race-free: identical byte ranges.
// ---------------------------------------------------------------------------
template<int PASS>
__global__ __launch_bounds__(256)
void scan_chunk(const float* __restrict__ u_, float* __restrict__ dty,
                const float* __restrict__ xdbl, const float* __restrict__ zb,
                const float* __restrict__ A_log, const float* __restrict__ Dp,
                float* __restrict__ hfin, float* __restrict__ sumdt)
{
  __shared__ __align__(16) float Tdt[TT][256];
  __shared__ __align__(16) float Tu [TT][256];
  __shared__ __align__(16) float Tz [TT][256];

  const int tid = threadIdx.x;
  const int idx = blockIdx.x*256 + tid;
  const int d = idx & (DINNER-1);
  const int g = idx >> 11;          // uniform per block
  const int cck = g & (NC-1);
  const int bb = g >> 5;
  const int wv = tid >> 6, ln = tid & 63;
  const int dbase = (blockIdx.x << 8) & (DINNER-1);

  float A2[16];
  {
    const float* al = A_log + (size_t)d*DSTATE;
    #pragma unroll
    for (int s=0;s<16;s++) A2[s] = -expf(al[s]) * 1.44269504f;
  }
  float h[16];
  if (PASS == 1){
    #pragma unroll
    for (int s=0;s<16;s++) h[s] = 0.f;
  } else {
    const float* hp = hfin + ((size_t)g*DINNER + d)*16;
    #pragma unroll
    for (int s=0;s<16;s+=4) *(float4*)&h[s] = *(const float4*)(hp + s);
  }
  const float Dv = (PASS==3) ? Dp[d] : 0.f;

  const size_t row0 = (size_t)bb*SEQL + (size_t)cck*TC;
  const float* pbc = xdbl + row0*96 + 64;

  float Bb[2][16], Cb[2][16];
#define LOAD_BC(buf, t) { const float4* p4 = (const float4*)(pbc + (size_t)(t)*96); \
    *(float4*)&Bb[buf][0]=p4[0]; *(float4*)&Bb[buf][4]=p4[1]; \
    *(float4*)&Bb[buf][8]=p4[2]; *(float4*)&Bb[buf][12]=p4[3]; \
    if (PASS==3){ \
    *(float4*)&Cb[buf][0]=p4[4]; *(float4*)&Cb[buf][4]=p4[5]; \
    *(float4*)&Cb[buf][8]=p4[6]; *(float4*)&Cb[buf][12]=p4[7]; } }

  LOAD_BC(0, 0);
  float sdt = 0.f;

  for (int t0 = 0; t0 < TC; t0 += TT){
    // ---- stage TT rows of dt/u/(z): per wave 2 rows, 1KB contiguous each
    #pragma unroll
    for (int q=0;q<2;q++){
      int r = q*4 + wv;
      size_t go = (row0 + t0 + r)*DINNER + dbase + ln*4;
      gld16(dty + go, &Tdt[r][0]);
      gld16(u_  + go, &Tu[r][0]);
      if (PASS==3) gld16(zb + go, &Tz[r][0]);
    }
    __syncthreads();

    #pragma unroll
    for (int tt=0; tt<TT; tt++){
      const int t = t0 + tt;
      const int cur = tt & 1, nxt = cur^1;   // compile-time (t0 even)
      float dtc = Tdt[tt][tid];
      float uc  = Tu[tt][tid];
      float zc  = (PASS==3) ? Tz[tt][tid] : 0.f;
      if (t+1 < TC) LOAD_BC(nxt, t+1);
      if (PASS==1) sdt += dtc;
      float du = dtc*uc;
      float y = 0.f;
      #pragma unroll
      for (int s=0;s<16;s++){
        float dA = exp2f(dtc*A2[s]);
        h[s] = fmaf(dA, h[s], du*Bb[cur][s]);
        if (PASS==3) y = fmaf(h[s], Cb[cur][s], y);
      }
      if (PASS==3){
        y = fmaf(uc, Dv, y);
        float gv = y * siluf(zc);
        unsigned short gh, gl;
        split_bf(gv, gh, gl);
        Tdt[tt][tid] = __uint_as_float((u32)gh | ((u32)gl << 16));
      }
    }

    if (PASS==3){
      __syncthreads();
      #pragma unroll
      for (int q=0;q<2;q++){
        int r = q*4 + wv;
        float4 v = *(const float4*)&Tdt[r][ln*4];
        *(float4*)(dty + (row0 + t0 + r)*DINNER + dbase + ln*4) = v;
      }
    }
    __syncthreads();
  }
#undef LOAD_BC

  if (PASS==1){
    float* hp = hfin + ((size_t)g*DINNER + d)*16;
    #pragma unroll
    for (int s=0;s<16;s+=4) *(float4*)(hp + s) = *(const float4*)&h[s];
    sumdt[(size_t)g*DINNER + d] = sdt;
  }
}

// ---------------------------------------------------------------------------
// Propagate chunk-initial states: in-place hfin[c] := H_init(c).
// ---------------------------------------------------------------------------
__global__ __launch_bounds__(256)
void scan_prop(const float* __restrict__ A_log, float* __restrict__ hfin,
               const float* __restrict__ sumdt)
{
  int idx = blockIdx.x*256 + threadIdx.x;
  int s = idx & 15;
  int d = (idx >> 4) & (DINNER-1);
  int b = idx >> 15;
  float A2 = -expf(A_log[(size_t)d*DSTATE + s]) * 1.44269504f;
  float H = 0.f;
  size_t hbase = ((size_t)b*NC*DINNER + d)*16 + s;
  size_t sbase = (size_t)b*NC*DINNER + d;
  for (int c=0;c<NC;c++){
    float P   = exp2f(A2 * sumdt[sbase + (size_t)c*DINNER]);
    float tmp = hfin[hbase + (size_t)c*DINNER*16];
    hfin[hbase + (size_t)c*DINNER*16] = H;
    H = fmaf(P, H, tmp);
  }
}

// ---------------------------------------------------------------------------
// Launcher.
// Fixed (68.7 MB): INW2 pair 33.55 + OUTW2 two-variant 33.55 + XPW2 1.57.
// Per batch (58.72 MB): SH 8.39 (aliases XD/HF/SD after in_proj) +
// XI 16.78 (xi -> dt -> packed gy) + ZB 16.78 + U 16.78.
// NB=4 -> 303.6 MB (known-good ws >= 305.1 MB).
// ---------------------------------------------------------------------------
extern "C" void kernel_launch(void* const* d_in, const int* in_sizes, int n_in,
                              void* d_out, int out_size, void* d_ws, size_t ws_size,
                              hipStream_t stream)
{
  const float* x    = (const float*)d_in[0];
  const float* in_w = (const float*)d_in[1];
  const float* cw   = (const float*)d_in[2];
  const float* cb   = (const float*)d_in[3];
  const float* xpw  = (const float*)d_in[4];
  const float* dtw  = (const float*)d_in[5];
  const float* dtb  = (const float*)d_in[6];
  const float* A_log= (const float*)d_in[7];
  const float* Dp   = (const float*)d_in[8];
  const float* ow   = (const float*)d_in[9];
  const float* nw   = (const float*)d_in[10];
  const float* nb   = (const float*)d_in[11];
  float* outF = (float*)d_out;

  const size_t fixedB = 33554432ULL + 33554432ULL + 1572864ULL;  // 68,681,728
  const size_t perB   = 58720256ULL;
  int NB = 4;
  while (NB > 1 && fixedB + (size_t)NB*perB > ws_size) NB >>= 1;
  const int Mc = NB * SEQL;
  const int nchunk = SEQB / NB;

  unsigned short* INW2  = (unsigned short*)d_ws;                 // [2][4096][2048]
  unsigned short* OUTW2 = INW2 + (size_t)2*4096*2048;            // [2][2][1024][4096]
  unsigned short* XPW2  = OUTW2 + (size_t)2*2*1024*4096;         // [2][96][4096]
  char* dyn = (char*)(XPW2 + (size_t)2*96*4096);

  unsigned short* SH = (unsigned short*)dyn;                     // Mc*2048 ushort
  float* XD = (float*)dyn;                                       // Mc*96  (alias SH)
  float* HF = (float*)(dyn + (size_t)Mc*384);                    // Mc*512 (alias SH)
  float* SD = (float*)(dyn + (size_t)Mc*2432);                   // Mc*32  (alias SH)
  float* XI = (float*)(dyn + (size_t)Mc*4096);                   // Mc*2048 f32
  float* ZB = XI + (size_t)Mc*2048;                              // Mc*2048
  float* U  = ZB + (size_t)Mc*2048;                              // Mc*2048

  // Weight pre-splits
  wsplit2<<<8192, 256, 0, stream>>>(in_w, INW2, 1024, 8);   // 8192 rows x K=1024
  wsplit2<<<384,  256, 0, stream>>>(xpw,  XPW2, 2048, 9);   // 192 rows x K=2048
  wsplit_ov<<<4096, 256, 0, stream>>>(ow, OUTW2);           // 2048 rows, 2 variants

  for (int c = 0; c < nchunk; ++c){
    const size_t rowoff = (size_t)c * Mc;
    const float* xrows = x + rowoff * DMODEL;
    float* X1 = outF + rowoff * DMODEL;     // layer-0 out / final out rows

    for (int l = 0; l < 2; ++l){
      const float* Al = A_log + (size_t)l*DINNER*DSTATE;

      // 1. LayerNorm (+ residual for layer 1) -> SH pair
      ln_split2<<<Mc, 256, 0, stream>>>(
          (l==0) ? xrows : X1, (l==0) ? nullptr : xrows,
          nw + (size_t)l*DMODEL, nb + (size_t)l*DMODEL, SH);

      // 2. in_proj fused xi|z: cols<2048 -> XI, cols>=2048 -> ZB
      mgemm_in<<<dim3(32, Mc/128), 256, 0, stream>>>(
          SH, INW2 + (size_t)l*4096*2048, XI, ZB);

      // 3. causal conv + bias + SiLU: XI -> U
      conv_silu_kernel<<<NB*4096, 256, 0, stream>>>(
          XI, cw + (size_t)l*DINNER*4, cb + (size_t)l*DINNER, U);

      // 4. x_proj (pre-split W) -> XD
      xproj_mfma<<<Mc/32, 256, 0, stream>>>(
          U, XPW2 + (size_t)l*96*4096, XD);

      // 5. dt_proj + bias + softplus -> XI (xi dead after conv)
      gemm_dt<<<dim3(16, Mc/128), 256, 0, stream>>>(
          XD, 96, dtw + (size_t)l*DINNER*64, 64, XI, DINNER, 64,
          dtb + (size_t)l*DINNER);

      // 6. chunked scan; pass 3 gates with z, writes PACKED gy over XI
      scan_chunk<1><<<NB*NC*8, 256, 0, stream>>>(
          U, XI, XD, ZB, Al, Dp + (size_t)l*DINNER, HF, SD);
      scan_prop<<<NB*128, 256, 0, stream>>>(Al, HF, SD);
      scan_chunk<3><<<NB*NC*8, 256, 0, stream>>>(
          U, XI, XD, ZB, Al, Dp + (size_t)l*DINNER, HF, SD);

      // 7. out_proj: packed-A x two-variant-B -> X1 rows
      mgemm_out<<<dim3(8, Mc/128), 256, 0, stream>>>(
          (const unsigned short*)XI, OUTW2 + (size_t)l*2*1024*4096, X1);
    }
  }
}

// Round 9
// 3953.107 us; speedup vs baseline: 1.0321x; 1.0321x over previous
//
#include <hip/hip_runtime.h>
#include <cstddef>
#include <cstdint>

// Problem constants (from reference)
#define SEQB   8
#define SEQL   2048
#define DMODEL 1024
#define DINNER 2048
#define DSTATE 16
#define NC     32            // scan chunks along t
#define TC     64            // SEQL/NC
#define TT     8             // scan LDS tile rows (t per stage)

typedef __attribute__((ext_vector_type(4))) float f32x4;
typedef __attribute__((ext_vector_type(8))) short bf16x8;
typedef unsigned int u32;
typedef const __attribute__((address_space(1))) u32* gas_ptr;
typedef __attribute__((address_space(3))) u32* las_ptr;

__device__ __forceinline__ void gld16(const void* g, void* l){
  __builtin_amdgcn_global_load_lds((gas_ptr)g, (las_ptr)l, 16, 0, 0);
}

__device__ __forceinline__ float siluf(float x){ return x / (1.f + __expf(-x)); }
__device__ __forceinline__ float softplusf(float x){ return (x > 20.f) ? x : log1pf(__expf(x)); }

// RNE fp32 -> bf16 bits
__device__ __forceinline__ unsigned short f2bf_rne(float f){
  unsigned int u = __float_as_uint(f);
  u += 0x7FFFu + ((u>>16)&1u);
  return (unsigned short)(u>>16);
}
__device__ __forceinline__ void split_bf(float f, unsigned short& h, unsigned short& l){
  unsigned short hs = f2bf_rne(f);
  float hf = __uint_as_float(((unsigned int)hs)<<16);
  h = hs;
  l = f2bf_rne(f - hf);
}

// ---------------------------------------------------------------------------
// Weight pre-split PAIR {h|l}: src [R][K] fp32 -> dst [R][2K] bf16.
// ---------------------------------------------------------------------------
__global__ __launch_bounds__(256)
void wsplit2(const float* __restrict__ src, unsigned short* __restrict__ dst,
             int K, int k4shift)
{
  int idx = blockIdx.x*256 + threadIdx.x;
  int r  = idx >> k4shift;
  int c4 = idx & ((1<<k4shift)-1);
  float4 v = ((const float4*)src)[idx];
  unsigned short h,l; short4 h4, l4;
  split_bf(v.x,h,l); h4.x=(short)h; l4.x=(short)l;
  split_bf(v.y,h,l); h4.y=(short)h; l4.y=(short)l;
  split_bf(v.z,h,l); h4.z=(short)h; l4.z=(short)l;
  split_bf(v.w,h,l); h4.w=(short)h; l4.w=(short)l;
  size_t ro = (size_t)r*2*K;
  *(short4*)&dst[ro + (c4<<2)]     = h4;
  *(short4*)&dst[ro + K + (c4<<2)] = l4;
}

// ---------------------------------------------------------------------------
// out_proj weight split, GROUPED pair layout matching scan's gy write:
// dst[layer][rr][512g + j]       = h' of W[rr][256g+j]
// dst[layer][rr][512g + 256 + j] = l'
// dst total: [2][1024][4096] ushort.
// ---------------------------------------------------------------------------
__global__ __launch_bounds__(256)
void wsplit_og(const float* __restrict__ src, unsigned short* __restrict__ dst)
{
  int idx = blockIdx.x*256 + threadIdx.x;    // per 4 elems; total 2*1024*2048/4
  int r  = idx >> 9;                         // 0..2047 (layer*1024 + rr)
  int c4 = idx & 511;
  int layer = r >> 10, rr = r & 1023;
  float4 v = ((const float4*)src)[idx];
  unsigned short h,l; short4 h4, l4;
  split_bf(v.x,h,l); h4.x=(short)h; l4.x=(short)l;
  split_bf(v.y,h,l); h4.y=(short)h; l4.y=(short)l;
  split_bf(v.z,h,l); h4.z=(short)h; l4.z=(short)l;
  split_bf(v.w,h,l); h4.w=(short)h; l4.w=(short)l;
  int col = c4 << 2;
  int g = col >> 8, j = col & 255;
  size_t base = (size_t)layer*1024*4096 + (size_t)rr*4096 + g*512 + j;
  *(short4*)&dst[base]       = h4;
  *(short4*)&dst[base + 256] = l4;
}

// ---------------------------------------------------------------------------
// LayerNorm (+ optional residual) fused with PAIR split {h|l}.
// ---------------------------------------------------------------------------
__global__ __launch_bounds__(256)
void ln_split2(const float* __restrict__ a, const float* __restrict__ res,
               const float* __restrict__ w, const float* __restrict__ bias,
               unsigned short* __restrict__ Hs)
{
  int row = blockIdx.x;
  size_t off = (size_t)row * DMODEL;
  float4 v = ((const float4*)(a + off))[threadIdx.x];
  if (res){
    float4 u = ((const float4*)(res + off))[threadIdx.x];
    v.x += u.x; v.y += u.y; v.z += u.z; v.w += u.w;
  }
  float s  = v.x + v.y + v.z + v.w;
  float s2 = fmaf(v.x,v.x, fmaf(v.y,v.y, fmaf(v.z,v.z, v.w*v.w)));
  #pragma unroll
  for (int o=32;o>0;o>>=1){ s += __shfl_down(s,o,64); s2 += __shfl_down(s2,o,64); }
  __shared__ float red[8];
  int lane = threadIdx.x & 63, wid = threadIdx.x >> 6;
  if (lane==0){ red[wid]=s; red[4+wid]=s2; }
  __syncthreads();
  s  = red[0]+red[1]+red[2]+red[3];
  s2 = red[4]+red[5]+red[6]+red[7];
  float mu  = s * (1.f/DMODEL);
  float var = s2 * (1.f/DMODEL) - mu*mu;
  float rstd = rsqrtf(var + 1e-5f);
  float4 wv = ((const float4*)w)[threadIdx.x];
  float4 bv = ((const float4*)bias)[threadIdx.x];
  float4 o4;
  o4.x = (v.x-mu)*rstd*wv.x + bv.x;
  o4.y = (v.y-mu)*rstd*wv.y + bv.y;
  o4.z = (v.z-mu)*rstd*wv.z + bv.z;
  o4.w = (v.w-mu)*rstd*wv.w + bv.w;
  unsigned short h,l; short4 h4, l4;
  split_bf(o4.x,h,l); h4.x=(short)h; l4.x=(short)l;
  split_bf(o4.y,h,l); h4.y=(short)h; l4.y=(short)l;
  split_bf(o4.z,h,l); h4.z=(short)h; l4.z=(short)l;
  split_bf(o4.w,h,l); h4.w=(short)h; l4.w=(short)l;
  size_t ro = (size_t)row*2048;
  int c = threadIdx.x<<2;
  *(short4*)&Hs[ro + c]        = h4;
  *(short4*)&Hs[ro + 1024 + c] = l4;
}

// ---------------------------------------------------------------------------
// in_proj GEMM (proven): pair-remap split-fp32, 3 virtual K=1024 passes.
// ---------------------------------------------------------------------------
__global__ __launch_bounds__(256)
void mgemm_in(const unsigned short* __restrict__ A,   // [M][2048] {h|l}
              const unsigned short* __restrict__ B,   // [4096][2048] {h|l}
              float* __restrict__ XI, float* __restrict__ ZB)
{
  __shared__ __align__(16) unsigned short As[128*32];
  __shared__ __align__(16) unsigned short Bs[128*32];
  const int t = threadIdx.x;
  const int mbase = blockIdx.y << 7, nbase = blockIdx.x << 7;
  const int lane = t & 63, w = t >> 6;
  const int wr = w >> 1, wc = w & 1;
  const int l16 = lane & 15, kq = lane >> 4;

  const int srow = t >> 2, sl = t & 3;
  const int co0 = ((sl ^ ((srow>>1)&3)) << 3);
  const int co1 = ((sl ^ (((srow+64)>>1)&3)) << 3);
  const unsigned short* pa0 = A + (size_t)(mbase+srow)*2048 + co0;
  const unsigned short* pa1 = A + (size_t)(mbase+srow+64)*2048 + co1;
  const unsigned short* pb0 = B + (size_t)(nbase+srow)*2048 + co0;
  const unsigned short* pb1 = B + (size_t)(nbase+srow+64)*2048 + co1;
  unsigned short* da0 = &As[srow*32 + sl*8];
  unsigned short* da1 = &As[(srow+64)*32 + sl*8];
  unsigned short* db0 = &Bs[srow*32 + sl*8];
  unsigned short* db1 = &Bs[(srow+64)*32 + sl*8];

  f32x4 acc[4][4];
  #pragma unroll
  for (int i=0;i<4;i++)
    #pragma unroll
    for (int j=0;j<4;j++) acc[i][j] = (f32x4){0.f,0.f,0.f,0.f};

  #pragma unroll
  for (int kb=0; kb<3; kb++){
    const int ao = (kb==2) ? 1024 : 0;   // A: {h,h,l}
    const int bo = (kb==1) ? 1024 : 0;   // B: {h,l,h}
    for (int kk=0; kk<1024; kk+=32){
      gld16(pa0 + ao + kk, da0);
      gld16(pa1 + ao + kk, da1);
      gld16(pb0 + bo + kk, db0);
      gld16(pb1 + bo + kk, db1);
      __syncthreads();
      bf16x8 af[4];
      #pragma unroll
      for (int mf=0; mf<4; mf++){
        int ra = wr*64 + mf*16 + l16;
        af[mf] = *(const bf16x8*)&As[ra*32 + ((kq ^ ((ra>>1)&3))<<3)];
      }
      #pragma unroll
      for (int nf=0; nf<4; nf++){
        int rb = wc*64 + nf*16 + l16;
        bf16x8 bfr = *(const bf16x8*)&Bs[rb*32 + ((kq ^ ((rb>>1)&3))<<3)];
        #pragma unroll
        for (int mf=0; mf<4; mf++)
          acc[mf][nf] = __builtin_amdgcn_mfma_f32_16x16x32_bf16(af[mf], bfr, acc[mf][nf], 0,0,0);
      }
      __syncthreads();
    }
  }

  float* Cd = (nbase < 2048) ? XI : ZB;
  const int cb = (nbase < 2048) ? nbase : (nbase - 2048);
  #pragma unroll
  for (int mf=0; mf<4; mf++){
    int r0 = mbase + wr*64 + mf*16 + kq*4;
    #pragma unroll
    for (int nf=0; nf<4; nf++){
      int c = cb + wc*64 + nf*16 + l16;
      #pragma unroll
      for (int r=0;r<4;r++)
        Cd[(size_t)(r0+r)*2048 + c] = acc[mf][nf][r];
    }
  }
}

// ---------------------------------------------------------------------------
// out_proj GEMM: A = gy grouped-plane ([M][4096] ushort: per 256-d group g,
// cols 512g..+255 = h, +256..511 = l), B = grouped pair ([1024][4096]).
// 3 virtual passes (hh, hl, lh) via per-group column-base remap. Raw = 3*K.
// ---------------------------------------------------------------------------
__global__ __launch_bounds__(256)
void mgemm_out3(const unsigned short* __restrict__ A,   // [M][4096] grouped
                const unsigned short* __restrict__ B,   // [1024][4096] grouped
                float* __restrict__ C)                  // [M][1024]
{
  __shared__ __align__(16) unsigned short As[128*32];
  __shared__ __align__(16) unsigned short Bs[128*32];
  const int t = threadIdx.x;
  const int mbase = blockIdx.y << 7, nbase = blockIdx.x << 7;
  const int lane = t & 63, w = t >> 6;
  const int wr = w >> 1, wc = w & 1;
  const int l16 = lane & 15, kq = lane >> 4;

  const int srow = t >> 2, sl = t & 3;
  const int co0 = ((sl ^ ((srow>>1)&3)) << 3);
  const int co1 = ((sl ^ (((srow+64)>>1)&3)) << 3);
  const unsigned short* pa0 = A + (size_t)(mbase+srow)*4096 + co0;
  const unsigned short* pa1 = A + (size_t)(mbase+srow+64)*4096 + co1;
  const unsigned short* pb0 = B + (size_t)(nbase+srow)*4096 + co0;
  const unsigned short* pb1 = B + (size_t)(nbase+srow+64)*4096 + co1;
  unsigned short* da0 = &As[srow*32 + sl*8];
  unsigned short* da1 = &As[(srow+64)*32 + sl*8];
  unsigned short* db0 = &Bs[srow*32 + sl*8];
  unsigned short* db1 = &Bs[(srow+64)*32 + sl*8];

  f32x4 acc[4][4];
  #pragma unroll
  for (int i=0;i<4;i++)
    #pragma unroll
    for (int j=0;j<4;j++) acc[i][j] = (f32x4){0.f,0.f,0.f,0.f};

  #pragma unroll
  for (int kb=0; kb<3; kb++){
    const int pa_ = (kb==2) ? 256 : 0;   // A plane: {h,h,l}
    const int pb_ = (kb==1) ? 256 : 0;   // B plane: {h,l,h}
    for (int v=0; v<2048; v+=32){
      const int gso = ((v>>8)<<9) + (v & 255);   // 512*g + j
      const int ao = gso + pa_;
      const int bo = gso + pb_;
      gld16(pa0 + ao, da0);
      gld16(pa1 + ao, da1);
      gld16(pb0 + bo, db0);
      gld16(pb1 + bo, db1);
      __syncthreads();
      bf16x8 af[4];
      #pragma unroll
      for (int mf=0; mf<4; mf++){
        int ra = wr*64 + mf*16 + l16;
        af[mf] = *(const bf16x8*)&As[ra*32 + ((kq ^ ((ra>>1)&3))<<3)];
      }
      #pragma unroll
      for (int nf=0; nf<4; nf++){
        int rb = wc*64 + nf*16 + l16;
        bf16x8 bfr = *(const bf16x8*)&Bs[rb*32 + ((kq ^ ((rb>>1)&3))<<3)];
        #pragma unroll
        for (int mf=0; mf<4; mf++)
          acc[mf][nf] = __builtin_amdgcn_mfma_f32_16x16x32_bf16(af[mf], bfr, acc[mf][nf], 0,0,0);
      }
      __syncthreads();
    }
  }

  #pragma unroll
  for (int mf=0; mf<4; mf++){
    int r0 = mbase + wr*64 + mf*16 + kq*4;
    #pragma unroll
    for (int nf=0; nf<4; nf++){
      int c = nbase + wc*64 + nf*16 + l16;
      #pragma unroll
      for (int r=0;r<4;r++)
        C[(size_t)(r0+r)*1024 + c] = acc[mf][nf][r];
    }
  }
}

// ---------------------------------------------------------------------------
// x_proj pure-pair GEMM: XD[m,n] = sum_k u[m,k]*W[n,k]; A = U2 pair
// ([M][4096] {h|l} planes), B = XPW2 pair ([96][4096]). 32x96 tile,
// 3 virtual K=2048 passes, all-gld16 staging. grid = M/32 blocks.
// ---------------------------------------------------------------------------
__global__ __launch_bounds__(256)
void xproj_pair(const unsigned short* __restrict__ A,
                const unsigned short* __restrict__ W2,
                float* __restrict__ XD)
{
  __shared__ __align__(16) unsigned short As_[32*32];
  __shared__ __align__(16) unsigned short Bs_[96*32];
  const int t = threadIdx.x;
  const int mbase = blockIdx.x << 5;
  const int lane = t & 63, w = t >> 6;
  const int mf = w & 1, nc0 = (w >> 1) * 48;
  const int l16 = lane & 15, kq = lane >> 4;

  // two 1KB loads per wave: L0 = w (A for w<2, else B rows 0..31),
  //                         L1 = w+4 (B rows 32..95)
  const bool isA0 = (w < 2);
  const int rr = lane >> 2, sl = lane & 3;
  const int r0_ = (isA0 ? 16*w : 16*(w-2)) + rr;
  const int sw0 = ((sl ^ ((r0_>>1)&3)) << 3);
  const unsigned short* base0 = isA0 ? (A + (size_t)(mbase+r0_)*4096 + sw0)
                                     : (W2 + (size_t)r0_*4096 + sw0);
  unsigned short* dst0 = isA0 ? (As_ + w*512 + lane*8)
                              : (Bs_ + (w-2)*512 + lane*8);
  const int r1_ = 16*(w+2) + rr;            // 32..95
  const int sw1 = ((sl ^ ((r1_>>1)&3)) << 3);
  const unsigned short* base1 = W2 + (size_t)r1_*4096 + sw1;
  unsigned short* dst1 = Bs_ + (w+2)*512 + lane*8;

  f32x4 acc[3];
  #pragma unroll
  for (int j=0;j<3;j++) acc[j] = (f32x4){0.f,0.f,0.f,0.f};

  #pragma unroll
  for (int kb=0; kb<3; kb++){
    const int ao = (kb==2) ? 2048 : 0;   // A: {h,h,l}
    const int bo = (kb==1) ? 2048 : 0;   // B: {h,l,h}
    const int off0 = isA0 ? ao : bo;
    for (int v=0; v<2048; v+=32){
      gld16(base0 + off0 + v, dst0);
      gld16(base1 + bo + v, dst1);
      __syncthreads();
      int ra = mf*16 + l16;
      bf16x8 a = *(const bf16x8*)&As_[ra*32 + ((kq ^ ((ra>>1)&3))<<3)];
      #pragma unroll
      for (int nf=0; nf<3; nf++){
        int rb = nc0 + nf*16 + l16;
        bf16x8 b = *(const bf16x8*)&Bs_[rb*32 + ((kq ^ ((rb>>1)&3))<<3)];
        acc[nf] = __builtin_amdgcn_mfma_f32_16x16x32_bf16(a, b, acc[nf], 0,0,0);
      }
      __syncthreads();
    }
  }
  #pragma unroll
  for (int nf=0; nf<3; nf++){
    int c = nc0 + nf*16 + l16;
    int r0s = mbase + mf*16 + kq*4;
    #pragma unroll
    for (int r=0;r<4;r++)
      XD[(size_t)(r0s+r)*96 + c] = acc[nf][r];
  }
}

// ---------------------------------------------------------------------------
// fp32 NT GEMM (dt_proj, K=64): C = softplus(A*B^T + ebias[n]).
// ---------------------------------------------------------------------------
__global__ __launch_bounds__(256)
void gemm_dt(const float* __restrict__ A, int lda,
             const float* __restrict__ B, int ldb,
             float* __restrict__ C, int ldc,
             int K, const float* __restrict__ ebias)
{
  __shared__ float As[16][132];
  __shared__ float Bs[16][132];
  int tid = threadIdx.x;
  int tx = tid & 15, ty = tid >> 4;
  int mbase = blockIdx.y << 7;
  int nbase = blockIdx.x << 7;
  float acc[8][8];
  #pragma unroll
  for (int i=0;i<8;i++)
    #pragma unroll
    for (int j=0;j<8;j++) acc[i][j]=0.f;

  for (int k0=0;k0<K;k0+=16){
    #pragma unroll
    for (int it=0; it<2; it++){
      int idx = tid + (it<<8);
      int row = idx >> 2;
      int kq  = (idx & 3) << 2;
      float4 va = *(const float4*)(A + (size_t)(mbase+row)*lda + k0 + kq);
      As[kq+0][row]=va.x; As[kq+1][row]=va.y; As[kq+2][row]=va.z; As[kq+3][row]=va.w;
      float4 vb = *(const float4*)(B + (size_t)(nbase+row)*ldb + k0 + kq);
      Bs[kq+0][row]=vb.x; Bs[kq+1][row]=vb.y; Bs[kq+2][row]=vb.z; Bs[kq+3][row]=vb.w;
    }
    __syncthreads();
    #pragma unroll
    for (int k=0;k<16;k++){
      float a[8], bb[8];
      *(float4*)&a[0]  = *(const float4*)&As[k][ty<<2];
      *(float4*)&a[4]  = *(const float4*)&As[k][64+(ty<<2)];
      *(float4*)&bb[0] = *(const float4*)&Bs[k][tx<<2];
      *(float4*)&bb[4] = *(const float4*)&Bs[k][64+(tx<<2)];
      #pragma unroll
      for (int i=0;i<8;i++)
        #pragma unroll
        for (int j=0;j<8;j++)
          acc[i][j] = fmaf(a[i], bb[j], acc[i][j]);
    }
    __syncthreads();
  }

  int n0 = nbase + (tx<<2);
  int n1 = n0 + 64;
  float4 eb0 = *(const float4*)(ebias + n0);
  float4 eb1 = *(const float4*)(ebias + n1);
  #pragma unroll
  for (int i=0;i<8;i++){
    int mrow = mbase + ((i<4) ? ((ty<<2)+i) : (64 + (ty<<2) + (i-4)));
    float4 c0 = make_float4(acc[i][0],acc[i][1],acc[i][2],acc[i][3]);
    float4 c1 = make_float4(acc[i][4],acc[i][5],acc[i][6],acc[i][7]);
    c0.x = softplusf(c0.x+eb0.x); c0.y = softplusf(c0.y+eb0.y);
    c0.z = softplusf(c0.z+eb0.z); c0.w = softplusf(c0.w+eb0.w);
    c1.x = softplusf(c1.x+eb1.x); c1.y = softplusf(c1.y+eb1.y);
    c1.z = softplusf(c1.z+eb1.z); c1.w = softplusf(c1.w+eb1.w);
    *(float4*)(C + (size_t)mrow*ldc + n0) = c0;
    *(float4*)(C + (size_t)mrow*ldc + n1) = c1;
  }
}

// ---------------------------------------------------------------------------
// Causal depthwise conv (k=4) + bias + SiLU: XI f32 -> U2 split pair
// ([M][4096] ushort: cols d = h, 2048+d = l).
// ---------------------------------------------------------------------------
__global__ __launch_bounds__(256)
void conv_silu_kernel(const float* __restrict__ xi, const float* __restrict__ cw,
                      const float* __restrict__ cb, unsigned short* __restrict__ u2)
{
  int idx = blockIdx.x*256 + threadIdx.x;
  int d = idx & (DINNER-1);
  int g = idx >> 11;
  int t0 = (g & 511) << 2;
  int b = g >> 9;
  float4 w4 = *(const float4*)(cw + d*4);
  float bias = cb[d];
  const float* base = xi + (size_t)b*SEQL*DINNER + d;
  float v[7];
  #pragma unroll
  for (int j=0;j<7;j++){
    int t = t0-3+j;
    v[j] = (t>=0) ? base[(size_t)t*DINNER] : 0.f;
  }
  unsigned short* outp = u2 + ((size_t)b*SEQL + t0)*4096 + d;
  #pragma unroll
  for (int j=0;j<4;j++){
    float y = fmaf(v[j+3], w4.w, fmaf(v[j+2], w4.z, fmaf(v[j+1], w4.y, fmaf(v[j], w4.x, bias))));
    float uv = siluf(y);
    unsigned short h,l;
    split_bf(uv, h, l);
    outp[(size_t)j*4096]        = h;
    outp[(size_t)j*4096 + 2048] = l;
  }
}

// ---------------------------------------------------------------------------
// Chunked selective scan, LDS-tiled, fully unrolled.
// u read from U2 pair (h+l reconstruct). PASS 3 writes gy as GROUPED planes
// (within the block-owned 1KB region: 512B h then 512B l) in place over dt.
// ---------------------------------------------------------------------------
template<int PASS>
__global__ __launch_bounds__(256)
void scan_chunk(const unsigned short* __restrict__ u2, float* __restrict__ dty,
                const float* __restrict__ xdbl, const float* __restrict__ zb,
                const float* __restrict__ A_log, const float* __restrict__ Dp,
                float* __restrict__ hfin, float* __restrict__ sumdt)
{
  __shared__ __align__(16) float Tdt[TT][256];
  __shared__ __align__(16) float Tu [TT][256];
  __shared__ __align__(16) float Tz [TT][256];

  const int tid = threadIdx.x;
  const int idx = blockIdx.x*256 + tid;
  const int d = idx & (DINNER-1);
  const int g = idx >> 11;          // uniform per block
  const int cck = g & (NC-1);
  const int bb = g >> 5;
  const int wv = tid >> 6, ln = tid & 63;
  const int dbase = (blockIdx.x << 8) & (DINNER-1);

  float A2[16];
  {
    const float* al = A_log + (size_t)d*DSTATE;
    #pragma unroll
    for (int s=0;s<16;s++) A2[s] = -expf(al[s]) * 1.44269504f;
  }
  float h[16];
  if (PASS == 1){
    #pragma unroll
    for (int s=0;s<16;s++) h[s] = 0.f;
  } else {
    const float* hp = hfin + ((size_t)g*DINNER + d)*16;
    #pragma unroll
    for (int s=0;s<16;s+=4) *(float4*)&h[s] = *(const float4*)(hp + s);
  }
  const float Dv = (PASS==3) ? Dp[d] : 0.f;

  const size_t row0 = (size_t)bb*SEQL + (size_t)cck*TC;
  const float* pbc = xdbl + row0*96 + 64;

  float Bb[2][16], Cb[2][16];
#define LOAD_BC(buf, t) { const float4* p4 = (const float4*)(pbc + (size_t)(t)*96); \
    *(float4*)&Bb[buf][0]=p4[0]; *(float4*)&Bb[buf][4]=p4[1]; \
    *(float4*)&Bb[buf][8]=p4[2]; *(float4*)&Bb[buf][12]=p4[3]; \
    if (PASS==3){ \
    *(float4*)&Cb[buf][0]=p4[4]; *(float4*)&Cb[buf][4]=p4[5]; \
    *(float4*)&Cb[buf][8]=p4[6]; *(float4*)&Cb[buf][12]=p4[7]; } }

  LOAD_BC(0, 0);
  float sdt = 0.f;

  for (int t0 = 0; t0 < TC; t0 += TT){
    #pragma unroll
    for (int q=0;q<2;q++){
      int r = q*4 + wv;
      size_t rowi = row0 + t0 + r;
      gld16(dty + rowi*2048 + dbase + ln*4, &Tdt[r][0]);
      // u pair: lanes 0..31 stage h half, 32..63 stage l half
      const unsigned short* us = u2 + rowi*4096 +
          ((ln < 32) ? (dbase + ln*8) : (2048 + dbase + (ln-32)*8));
      gld16(us, &Tu[r][0]);
      if (PASS==3) gld16(zb + rowi*2048 + dbase + ln*4, &Tz[r][0]);
    }
    __syncthreads();

    #pragma unroll
    for (int tt=0; tt<TT; tt++){
      const int t = t0 + tt;
      const int cur = tt & 1, nxt = cur^1;   // compile-time
      float dtc = Tdt[tt][tid];
      const unsigned short* tur = (const unsigned short*)&Tu[tt][0];
      float uc = __uint_as_float((u32)tur[tid] << 16)
               + __uint_as_float((u32)tur[256+tid] << 16);
      float zc  = (PASS==3) ? Tz[tt][tid] : 0.f;
      if (t+1 < TC) LOAD_BC(nxt, t+1);
      if (PASS==1) sdt += dtc;
      float du = dtc*uc;
      float y = 0.f;
      #pragma unroll
      for (int s=0;s<16;s++){
        float dA = exp2f(dtc*A2[s]);
        h[s] = fmaf(dA, h[s], du*Bb[cur][s]);
        if (PASS==3) y = fmaf(h[s], Cb[cur][s], y);
      }
      if (PASS==3){
        y = fmaf(uc, Dv, y);
        float gv = y * siluf(zc);
        unsigned short gh, gl;
        split_bf(gv, gh, gl);
        Tdt[tt][tid] = __uint_as_float((u32)gh | ((u32)gl << 16));
      }
    }

    if (PASS==3){
      __syncthreads();
      #pragma unroll
      for (int q=0;q<2;q++){
        int r = q*4 + wv;
        size_t rowi = row0 + t0 + r;
        const u32* T = (const u32*)&Tdt[r][0];
        int o0 = ln*4;
        u32 vals[4];
        if (ln < 32){
          #pragma unroll
          for (int k=0;k<4;k++){
            int i2 = (o0+k)*2;
            vals[k] = (T[i2] & 0xFFFFu) | (T[i2+1] << 16);
          }
        } else {
          #pragma unroll
          for (int k=0;k<4;k++){
            int i2 = (o0+k-128)*2;
            vals[k] = (T[i2] >> 16) | (T[i2+1] & 0xFFFF0000u);
          }
        }
        *(float4*)(dty + rowi*2048 + dbase + o0) = *(const float4*)vals;
      }
    }
    __syncthreads();
  }
#undef LOAD_BC

  if (PASS==1){
    float* hp = hfin + ((size_t)g*DINNER + d)*16;
    #pragma unroll
    for (int s=0;s<16;s+=4) *(float4*)(hp + s) = *(const float4*)&h[s];
    sumdt[(size_t)g*DINNER + d] = sdt;
  }
}

// ---------------------------------------------------------------------------
// Propagate chunk-initial states: in-place hfin[c] := H_init(c).
// ---------------------------------------------------------------------------
__global__ __launch_bounds__(256)
void scan_prop(const float* __restrict__ A_log, float* __restrict__ hfin,
               const float* __restrict__ sumdt)
{
  int idx = blockIdx.x*256 + threadIdx.x;
  int s = idx & 15;
  int d = (idx >> 4) & (DINNER-1);
  int b = idx >> 15;
  float A2 = -expf(A_log[(size_t)d*DSTATE + s]) * 1.44269504f;
  float H = 0.f;
  size_t hbase = ((size_t)b*NC*DINNER + d)*16 + s;
  size_t sbase = (size_t)b*NC*DINNER + d;
  for (int c=0;c<NC;c++){
    float P   = exp2f(A2 * sumdt[sbase + (size_t)c*DINNER]);
    float tmp = hfin[hbase + (size_t)c*DINNER*16];
    hfin[hbase + (size_t)c*DINNER*16] = H;
    H = fmaf(P, H, tmp);
  }
}

// ---------------------------------------------------------------------------
// Launcher.
// Fixed (51.9 MB): INW2 33.55 + OUTWG 16.78 + XPW2 1.57.
// Per batch (58.72 MB): SH 8.39 (aliases XD/HF/SD) + XI 16.78 + ZB 16.78 +
// U2 16.78.  NB=4 -> 286.8 MB (< 305.1 known-good).
// ---------------------------------------------------------------------------
extern "C" void kernel_launch(void* const* d_in, const int* in_sizes, int n_in,
                              void* d_out, int out_size, void* d_ws, size_t ws_size,
                              hipStream_t stream)
{
  const float* x    = (const float*)d_in[0];
  const float* in_w = (const float*)d_in[1];
  const float* cw   = (const float*)d_in[2];
  const float* cb   = (const float*)d_in[3];
  const float* xpw  = (const float*)d_in[4];
  const float* dtw  = (const float*)d_in[5];
  const float* dtb  = (const float*)d_in[6];
  const float* A_log= (const float*)d_in[7];
  const float* Dp   = (const float*)d_in[8];
  const float* ow   = (const float*)d_in[9];
  const float* nw   = (const float*)d_in[10];
  const float* nb   = (const float*)d_in[11];
  float* outF = (float*)d_out;

  const size_t fixedB = 33554432ULL + 16777216ULL + 1572864ULL;  // 51,904,512
  const size_t perB   = 58720256ULL;
  int NB = 4;
  while (NB > 1 && fixedB + (size_t)NB*perB > ws_size) NB >>= 1;
  const int Mc = NB * SEQL;
  const int nchunk = SEQB / NB;

  unsigned short* INW2  = (unsigned short*)d_ws;                 // [2][4096][2048]
  unsigned short* OUTWG = INW2 + (size_t)2*4096*2048;            // [2][1024][4096]
  unsigned short* XPW2  = OUTWG + (size_t)2*1024*4096;           // [2][96][4096]
  char* dyn = (char*)(XPW2 + (size_t)2*96*4096);

  unsigned short* SH = (unsigned short*)dyn;                     // Mc*2048 ushort
  float* XD = (float*)dyn;                                       // Mc*96  (alias SH)
  float* HF = (float*)(dyn + (size_t)Mc*384);                    // Mc*512 (alias SH)
  float* SD = (float*)(dyn + (size_t)Mc*2432);                   // Mc*32  (alias SH)
  float* XI = (float*)(dyn + (size_t)Mc*4096);                   // Mc*2048 f32
  float* ZB = XI + (size_t)Mc*2048;                              // Mc*2048
  unsigned short* U2 = (unsigned short*)(ZB + (size_t)Mc*2048);  // Mc*4096 ushort

  // Weight pre-splits
  wsplit2<<<8192, 256, 0, stream>>>(in_w, INW2, 1024, 8);
  wsplit2<<<384,  256, 0, stream>>>(xpw,  XPW2, 2048, 9);
  wsplit_og<<<4096, 256, 0, stream>>>(ow, OUTWG);

  for (int c = 0; c < nchunk; ++c){
    const size_t rowoff = (size_t)c * Mc;
    const float* xrows = x + rowoff * DMODEL;
    float* X1 = outF + rowoff * DMODEL;     // layer-0 out / final out rows

    for (int l = 0; l < 2; ++l){
      const float* Al = A_log + (size_t)l*DINNER*DSTATE;

      // 1. LayerNorm (+ residual for layer 1) -> SH pair
      ln_split2<<<Mc, 256, 0, stream>>>(
          (l==0) ? xrows : X1, (l==0) ? nullptr : xrows,
          nw + (size_t)l*DMODEL, nb + (size_t)l*DMODEL, SH);

      // 2. in_proj fused xi|z: cols<2048 -> XI, cols>=2048 -> ZB
      mgemm_in<<<dim3(32, Mc/128), 256, 0, stream>>>(
          SH, INW2 + (size_t)l*4096*2048, XI, ZB);

      // 3. causal conv + bias + SiLU: XI -> U2 (split pair)
      conv_silu_kernel<<<NB*4096, 256, 0, stream>>>(
          XI, cw + (size_t)l*DINNER*4, cb + (size_t)l*DINNER, U2);

      // 4. x_proj (pure pair GEMM) -> XD
      xproj_pair<<<Mc/32, 256, 0, stream>>>(
          U2, XPW2 + (size_t)l*96*4096, XD);

      // 5. dt_proj + bias + softplus -> XI (xi dead after conv)
      gemm_dt<<<dim3(16, Mc/128), 256, 0, stream>>>(
          XD, 96, dtw + (size_t)l*DINNER*64, 64, XI, DINNER, 64,
          dtb + (size_t)l*DINNER);

      // 6. chunked scan; pass 3 writes grouped-plane gy over XI
      scan_chunk<1><<<NB*NC*8, 256, 0, stream>>>(
          U2, XI, XD, ZB, Al, Dp + (size_t)l*DINNER, HF, SD);
      scan_prop<<<NB*128, 256, 0, stream>>>(Al, HF, SD);
      scan_chunk<3><<<NB*NC*8, 256, 0, stream>>>(
          U2, XI, XD, ZB, Al, Dp + (size_t)l*DINNER, HF, SD);

      // 7. out_proj: grouped-A x grouped-B, 3 virtual passes -> X1 rows
      mgemm_out3<<<dim3(8, Mc/128), 256, 0, stream>>>(
          (const unsigned short*)XI, OUTWG + (size_t)l*1024*4096, X1);
    }
  }
}

// Round 10
// 3604.403 us; speedup vs baseline: 1.1319x; 1.0967x over previous
//
#include <hip/hip_runtime.h>
#include <cstddef>
#include <cstdint>

// Problem constants (from reference)
#define SEQB   8
#define SEQL   2048
#define DMODEL 1024
#define DINNER 2048
#define DSTATE 16
#define NC     32            // scan chunks along t
#define TC     64            // SEQL/NC
#define TT     8             // scan LDS tile rows (t per stage)

typedef __attribute__((ext_vector_type(4))) float f32x4;
typedef __attribute__((ext_vector_type(8))) short bf16x8;
typedef unsigned int u32;
typedef const __attribute__((address_space(1))) u32* gas_ptr;
typedef __attribute__((address_space(3))) u32* las_ptr;

__device__ __forceinline__ void gld16(const void* g, void* l){
  __builtin_amdgcn_global_load_lds((gas_ptr)g, (las_ptr)l, 16, 0, 0);
}

__device__ __forceinline__ float siluf(float x){ return x / (1.f + __expf(-x)); }
__device__ __forceinline__ float softplusf(float x){ return (x > 20.f) ? x : log1pf(__expf(x)); }

// RNE fp32 -> bf16 bits
__device__ __forceinline__ unsigned short f2bf_rne(float f){
  unsigned int u = __float_as_uint(f);
  u += 0x7FFFu + ((u>>16)&1u);
  return (unsigned short)(u>>16);
}
__device__ __forceinline__ void split_bf(float f, unsigned short& h, unsigned short& l){
  unsigned short hs = f2bf_rne(f);
  float hf = __uint_as_float(((unsigned int)hs)<<16);
  h = hs;
  l = f2bf_rne(f - hf);
}

// ---------------------------------------------------------------------------
// Weight pre-split PAIR {h|l}: src [R][K] fp32 -> dst [R][2K] bf16.
// ---------------------------------------------------------------------------
__global__ __launch_bounds__(256)
void wsplit2(const float* __restrict__ src, unsigned short* __restrict__ dst,
             int K, int k4shift)
{
  int idx = blockIdx.x*256 + threadIdx.x;
  int r  = idx >> k4shift;
  int c4 = idx & ((1<<k4shift)-1);
  float4 v = ((const float4*)src)[idx];
  unsigned short h,l; short4 h4, l4;
  split_bf(v.x,h,l); h4.x=(short)h; l4.x=(short)l;
  split_bf(v.y,h,l); h4.y=(short)h; l4.y=(short)l;
  split_bf(v.z,h,l); h4.z=(short)h; l4.z=(short)l;
  split_bf(v.w,h,l); h4.w=(short)h; l4.w=(short)l;
  size_t ro = (size_t)r*2*K;
  *(short4*)&dst[ro + (c4<<2)]     = h4;
  *(short4*)&dst[ro + K + (c4<<2)] = l4;
}

// ---------------------------------------------------------------------------
// out_proj weight split, GROUPED pair layout matching scan's gy write:
// dst[layer][rr][512g + j] = h', dst[layer][rr][512g + 256 + j] = l'.
// ---------------------------------------------------------------------------
__global__ __launch_bounds__(256)
void wsplit_og(const float* __restrict__ src, unsigned short* __restrict__ dst)
{
  int idx = blockIdx.x*256 + threadIdx.x;
  int r  = idx >> 9;
  int c4 = idx & 511;
  int layer = r >> 10, rr = r & 1023;
  float4 v = ((const float4*)src)[idx];
  unsigned short h,l; short4 h4, l4;
  split_bf(v.x,h,l); h4.x=(short)h; l4.x=(short)l;
  split_bf(v.y,h,l); h4.y=(short)h; l4.y=(short)l;
  split_bf(v.z,h,l); h4.z=(short)h; l4.z=(short)l;
  split_bf(v.w,h,l); h4.w=(short)h; l4.w=(short)l;
  int col = c4 << 2;
  int g = col >> 8, j = col & 255;
  size_t base = (size_t)layer*1024*4096 + (size_t)rr*4096 + g*512 + j;
  *(short4*)&dst[base]       = h4;
  *(short4*)&dst[base + 256] = l4;
}

// ---------------------------------------------------------------------------
// LayerNorm (+ optional residual) fused with PAIR split {h|l}.
// ---------------------------------------------------------------------------
__global__ __launch_bounds__(256)
void ln_split2(const float* __restrict__ a, const float* __restrict__ res,
               const float* __restrict__ w, const float* __restrict__ bias,
               unsigned short* __restrict__ Hs)
{
  int row = blockIdx.x;
  size_t off = (size_t)row * DMODEL;
  float4 v = ((const float4*)(a + off))[threadIdx.x];
  if (res){
    float4 u = ((const float4*)(res + off))[threadIdx.x];
    v.x += u.x; v.y += u.y; v.z += u.z; v.w += u.w;
  }
  float s  = v.x + v.y + v.z + v.w;
  float s2 = fmaf(v.x,v.x, fmaf(v.y,v.y, fmaf(v.z,v.z, v.w*v.w)));
  #pragma unroll
  for (int o=32;o>0;o>>=1){ s += __shfl_down(s,o,64); s2 += __shfl_down(s2,o,64); }
  __shared__ float red[8];
  int lane = threadIdx.x & 63, wid = threadIdx.x >> 6;
  if (lane==0){ red[wid]=s; red[4+wid]=s2; }
  __syncthreads();
  s  = red[0]+red[1]+red[2]+red[3];
  s2 = red[4]+red[5]+red[6]+red[7];
  float mu  = s * (1.f/DMODEL);
  float var = s2 * (1.f/DMODEL) - mu*mu;
  float rstd = rsqrtf(var + 1e-5f);
  float4 wv = ((const float4*)w)[threadIdx.x];
  float4 bv = ((const float4*)bias)[threadIdx.x];
  float4 o4;
  o4.x = (v.x-mu)*rstd*wv.x + bv.x;
  o4.y = (v.y-mu)*rstd*wv.y + bv.y;
  o4.z = (v.z-mu)*rstd*wv.z + bv.z;
  o4.w = (v.w-mu)*rstd*wv.w + bv.w;
  unsigned short h,l; short4 h4, l4;
  split_bf(o4.x,h,l); h4.x=(short)h; l4.x=(short)l;
  split_bf(o4.y,h,l); h4.y=(short)h; l4.y=(short)l;
  split_bf(o4.z,h,l); h4.z=(short)h; l4.z=(short)l;
  split_bf(o4.w,h,l); h4.w=(short)h; l4.w=(short)l;
  size_t ro = (size_t)row*2048;
  int c = threadIdx.x<<2;
  *(short4*)&Hs[ro + c]        = h4;
  *(short4*)&Hs[ro + 1024 + c] = l4;
}

// ---------------------------------------------------------------------------
// in_proj GEMM: pair-remap split-fp32, 3 virtual K=1024 passes.
// BK=64 (halved barrier count vs BK=32), 3-bit XOR swizzle (row stride 128B
// = bank period; slot ^= row&7 -> consecutive-8 lanes hit all 32 banks).
// XCD-aware bijective block swizzle (total blocks % 8 == 0).
// Epilogue splits cols: n<2048 -> XI, else -> ZB. M,N mult of 128.
// ---------------------------------------------------------------------------
__global__ __launch_bounds__(256)
void mgemm_in(const unsigned short* __restrict__ A,   // [M][2048] {h|l}
              const unsigned short* __restrict__ B,   // [4096][2048] {h|l}
              float* __restrict__ XI, float* __restrict__ ZB)
{
  __shared__ __align__(16) unsigned short As[128*64];
  __shared__ __align__(16) unsigned short Bs[128*64];
  const int t = threadIdx.x;
  // T1: XCD-aware swizzle
  const int nbx = 32;
  const int total = nbx * gridDim.y;
  const int wg = blockIdx.y * nbx + blockIdx.x;
  const int swz = (wg & 7) * (total >> 3) + (wg >> 3);
  const int mbase = (swz / nbx) << 7;
  const int nbase = (swz % nbx) << 7;

  const int lane = t & 63, w = t >> 6;
  const int wr = w >> 1, wc = w & 1;
  const int l16 = lane & 15, kq = lane >> 4;

  // staging: 4 calls per matrix; call c, wave w: rows c*32+w*8+lane/8
  const int sr8 = lane >> 3, sl8 = lane & 7;
  const unsigned short* pA[4]; const unsigned short* pB[4];
  unsigned short* dA[4]; unsigned short* dB[4];
  #pragma unroll
  for (int c=0;c<4;c++){
    int row = c*32 + w*8 + sr8;
    int col = (sl8 ^ (row & 7)) << 3;
    pA[c] = A + (size_t)(mbase+row)*2048 + col;
    pB[c] = B + (size_t)(nbase+row)*2048 + col;
    dA[c] = &As[row*64 + sl8*8];
    dB[c] = &Bs[row*64 + sl8*8];
  }

  f32x4 acc[4][4];
  #pragma unroll
  for (int i=0;i<4;i++)
    #pragma unroll
    for (int j=0;j<4;j++) acc[i][j] = (f32x4){0.f,0.f,0.f,0.f};

  #pragma unroll
  for (int kb=0; kb<3; kb++){
    const int ao = (kb==2) ? 1024 : 0;   // A: {h,h,l}
    const int bo = (kb==1) ? 1024 : 0;   // B: {h,l,h}
    for (int kk=0; kk<1024; kk+=64){
      #pragma unroll
      for (int c=0;c<4;c++){
        gld16(pA[c] + ao + kk, dA[c]);
        gld16(pB[c] + bo + kk, dB[c]);
      }
      __syncthreads();
      #pragma unroll
      for (int ks=0; ks<2; ks++){
        const int kcol = kq + ks*4;
        bf16x8 af[4];
        #pragma unroll
        for (int mf=0; mf<4; mf++){
          int ra = wr*64 + mf*16 + l16;
          af[mf] = *(const bf16x8*)&As[ra*64 + ((kcol ^ (ra&7))<<3)];
        }
        #pragma unroll
        for (int nf=0; nf<4; nf++){
          int rb = wc*64 + nf*16 + l16;
          bf16x8 bfr = *(const bf16x8*)&Bs[rb*64 + ((kcol ^ (rb&7))<<3)];
          #pragma unroll
          for (int mf=0; mf<4; mf++)
            acc[mf][nf] = __builtin_amdgcn_mfma_f32_16x16x32_bf16(af[mf], bfr, acc[mf][nf], 0,0,0);
        }
      }
      __syncthreads();
    }
  }

  float* Cd = (nbase < 2048) ? XI : ZB;
  const int cb = (nbase < 2048) ? nbase : (nbase - 2048);
  #pragma unroll
  for (int mf=0; mf<4; mf++){
    int r0 = mbase + wr*64 + mf*16 + kq*4;
    #pragma unroll
    for (int nf=0; nf<4; nf++){
      int c = cb + wc*64 + nf*16 + l16;
      #pragma unroll
      for (int r=0;r<4;r++)
        Cd[(size_t)(r0+r)*2048 + c] = acc[mf][nf][r];
    }
  }
}

// ---------------------------------------------------------------------------
// out_proj GEMM: A = gy grouped-plane ([M][4096]: per 256-d group g, cols
// 512g..+255 = h, +256..511 = l), B = grouped pair ([1024][4096]).
// 3 virtual passes via plane remap. BK=64 + 3-bit swizzle + XCD swizzle.
// ---------------------------------------------------------------------------
__global__ __launch_bounds__(256)
void mgemm_out3(const unsigned short* __restrict__ A,   // [M][4096] grouped
                const unsigned short* __restrict__ B,   // [1024][4096] grouped
                float* __restrict__ C)                  // [M][1024]
{
  __shared__ __align__(16) unsigned short As[128*64];
  __shared__ __align__(16) unsigned short Bs[128*64];
  const int t = threadIdx.x;
  const int nbx = 8;
  const int total = nbx * gridDim.y;
  const int wg = blockIdx.y * nbx + blockIdx.x;
  const int swz = (wg & 7) * (total >> 3) + (wg >> 3);
  const int mbase = (swz / nbx) << 7;
  const int nbase = (swz % nbx) << 7;

  const int lane = t & 63, w = t >> 6;
  const int wr = w >> 1, wc = w & 1;
  const int l16 = lane & 15, kq = lane >> 4;

  const int sr8 = lane >> 3, sl8 = lane & 7;
  const unsigned short* pA[4]; const unsigned short* pB[4];
  unsigned short* dA[4]; unsigned short* dB[4];
  #pragma unroll
  for (int c=0;c<4;c++){
    int row = c*32 + w*8 + sr8;
    int col = (sl8 ^ (row & 7)) << 3;
    pA[c] = A + (size_t)(mbase+row)*4096 + col;
    pB[c] = B + (size_t)(nbase+row)*4096 + col;
    dA[c] = &As[row*64 + sl8*8];
    dB[c] = &Bs[row*64 + sl8*8];
  }

  f32x4 acc[4][4];
  #pragma unroll
  for (int i=0;i<4;i++)
    #pragma unroll
    for (int j=0;j<4;j++) acc[i][j] = (f32x4){0.f,0.f,0.f,0.f};

  #pragma unroll
  for (int kb=0; kb<3; kb++){
    const int pa_ = (kb==2) ? 256 : 0;   // A plane: {h,h,l}
    const int pb_ = (kb==1) ? 256 : 0;   // B plane: {h,l,h}
    for (int v=0; v<2048; v+=64){
      const int gso = ((v>>8)<<9) + (v & 255);   // 512*g + j (64-aligned)
      #pragma unroll
      for (int c=0;c<4;c++){
        gld16(pA[c] + gso + pa_, dA[c]);
        gld16(pB[c] + gso + pb_, dB[c]);
      }
      __syncthreads();
      #pragma unroll
      for (int ks=0; ks<2; ks++){
        const int kcol = kq + ks*4;
        bf16x8 af[4];
        #pragma unroll
        for (int mf=0; mf<4; mf++){
          int ra = wr*64 + mf*16 + l16;
          af[mf] = *(const bf16x8*)&As[ra*64 + ((kcol ^ (ra&7))<<3)];
        }
        #pragma unroll
        for (int nf=0; nf<4; nf++){
          int rb = wc*64 + nf*16 + l16;
          bf16x8 bfr = *(const bf16x8*)&Bs[rb*64 + ((kcol ^ (rb&7))<<3)];
          #pragma unroll
          for (int mf=0; mf<4; mf++)
            acc[mf][nf] = __builtin_amdgcn_mfma_f32_16x16x32_bf16(af[mf], bfr, acc[mf][nf], 0,0,0);
        }
      }
      __syncthreads();
    }
  }

  #pragma unroll
  for (int mf=0; mf<4; mf++){
    int r0 = mbase + wr*64 + mf*16 + kq*4;
    #pragma unroll
    for (int nf=0; nf<4; nf++){
      int c = nbase + wc*64 + nf*16 + l16;
      #pragma unroll
      for (int r=0;r<4;r++)
        C[(size_t)(r0+r)*1024 + c] = acc[mf][nf][r];
    }
  }
}

// ---------------------------------------------------------------------------
// x_proj pure-pair GEMM (unchanged from round 9).
// ---------------------------------------------------------------------------
__global__ __launch_bounds__(256)
void xproj_pair(const unsigned short* __restrict__ A,
                const unsigned short* __restrict__ W2,
                float* __restrict__ XD)
{
  __shared__ __align__(16) unsigned short As_[32*32];
  __shared__ __align__(16) unsigned short Bs_[96*32];
  const int t = threadIdx.x;
  const int mbase = blockIdx.x << 5;
  const int lane = t & 63, w = t >> 6;
  const int mf = w & 1, nc0 = (w >> 1) * 48;
  const int l16 = lane & 15, kq = lane >> 4;

  const bool isA0 = (w < 2);
  const int rr = lane >> 2, sl = lane & 3;
  const int r0_ = (isA0 ? 16*w : 16*(w-2)) + rr;
  const int sw0 = ((sl ^ ((r0_>>1)&3)) << 3);
  const unsigned short* base0 = isA0 ? (A + (size_t)(mbase+r0_)*4096 + sw0)
                                     : (W2 + (size_t)r0_*4096 + sw0);
  unsigned short* dst0 = isA0 ? (As_ + w*512 + lane*8)
                              : (Bs_ + (w-2)*512 + lane*8);
  const int r1_ = 16*(w+2) + rr;            // 32..95
  const int sw1 = ((sl ^ ((r1_>>1)&3)) << 3);
  const unsigned short* base1 = W2 + (size_t)r1_*4096 + sw1;
  unsigned short* dst1 = Bs_ + (w+2)*512 + lane*8;

  f32x4 acc[3];
  #pragma unroll
  for (int j=0;j<3;j++) acc[j] = (f32x4){0.f,0.f,0.f,0.f};

  #pragma unroll
  for (int kb=0; kb<3; kb++){
    const int ao = (kb==2) ? 2048 : 0;   // A: {h,h,l}
    const int bo = (kb==1) ? 2048 : 0;   // B: {h,l,h}
    const int off0 = isA0 ? ao : bo;
    for (int v=0; v<2048; v+=32){
      gld16(base0 + off0 + v, dst0);
      gld16(base1 + bo + v, dst1);
      __syncthreads();
      int ra = mf*16 + l16;
      bf16x8 a = *(const bf16x8*)&As_[ra*32 + ((kq ^ ((ra>>1)&3))<<3)];
      #pragma unroll
      for (int nf=0; nf<3; nf++){
        int rb = nc0 + nf*16 + l16;
        bf16x8 b = *(const bf16x8*)&Bs_[rb*32 + ((kq ^ ((rb>>1)&3))<<3)];
        acc[nf] = __builtin_amdgcn_mfma_f32_16x16x32_bf16(a, b, acc[nf], 0,0,0);
      }
      __syncthreads();
    }
  }
  #pragma unroll
  for (int nf=0; nf<3; nf++){
    int c = nc0 + nf*16 + l16;
    int r0s = mbase + mf*16 + kq*4;
    #pragma unroll
    for (int r=0;r<4;r++)
      XD[(size_t)(r0s+r)*96 + c] = acc[nf][r];
  }
}

// ---------------------------------------------------------------------------
// fp32 NT GEMM (dt_proj, K=64): C = softplus(A*B^T + ebias[n]).
// ---------------------------------------------------------------------------
__global__ __launch_bounds__(256)
void gemm_dt(const float* __restrict__ A, int lda,
             const float* __restrict__ B, int ldb,
             float* __restrict__ C, int ldc,
             int K, const float* __restrict__ ebias)
{
  __shared__ float As[16][132];
  __shared__ float Bs[16][132];
  int tid = threadIdx.x;
  int tx = tid & 15, ty = tid >> 4;
  int mbase = blockIdx.y << 7;
  int nbase = blockIdx.x << 7;
  float acc[8][8];
  #pragma unroll
  for (int i=0;i<8;i++)
    #pragma unroll
    for (int j=0;j<8;j++) acc[i][j]=0.f;

  for (int k0=0;k0<K;k0+=16){
    #pragma unroll
    for (int it=0; it<2; it++){
      int idx = tid + (it<<8);
      int row = idx >> 2;
      int kq  = (idx & 3) << 2;
      float4 va = *(const float4*)(A + (size_t)(mbase+row)*lda + k0 + kq);
      As[kq+0][row]=va.x; As[kq+1][row]=va.y; As[kq+2][row]=va.z; As[kq+3][row]=va.w;
      float4 vb = *(const float4*)(B + (size_t)(nbase+row)*ldb + k0 + kq);
      Bs[kq+0][row]=vb.x; Bs[kq+1][row]=vb.y; Bs[kq+2][row]=vb.z; Bs[kq+3][row]=vb.w;
    }
    __syncthreads();
    #pragma unroll
    for (int k=0;k<16;k++){
      float a[8], bb[8];
      *(float4*)&a[0]  = *(const float4*)&As[k][ty<<2];
      *(float4*)&a[4]  = *(const float4*)&As[k][64+(ty<<2)];
      *(float4*)&bb[0] = *(const float4*)&Bs[k][tx<<2];
      *(float4*)&bb[4] = *(const float4*)&Bs[k][64+(tx<<2)];
      #pragma unroll
      for (int i=0;i<8;i++)
        #pragma unroll
        for (int j=0;j<8;j++)
          acc[i][j] = fmaf(a[i], bb[j], acc[i][j]);
    }
    __syncthreads();
  }

  int n0 = nbase + (tx<<2);
  int n1 = n0 + 64;
  float4 eb0 = *(const float4*)(ebias + n0);
  float4 eb1 = *(const float4*)(ebias + n1);
  #pragma unroll
  for (int i=0;i<8;i++){
    int mrow = mbase + ((i<4) ? ((ty<<2)+i) : (64 + (ty<<2) + (i-4)));
    float4 c0 = make_float4(acc[i][0],acc[i][1],acc[i][2],acc[i][3]);
    float4 c1 = make_float4(acc[i][4],acc[i][5],acc[i][6],acc[i][7]);
    c0.x = softplusf(c0.x+eb0.x); c0.y = softplusf(c0.y+eb0.y);
    c0.z = softplusf(c0.z+eb0.z); c0.w = softplusf(c0.w+eb0.w);
    c1.x = softplusf(c1.x+eb1.x); c1.y = softplusf(c1.y+eb1.y);
    c1.z = softplusf(c1.z+eb1.z); c1.w = softplusf(c1.w+eb1.w);
    *(float4*)(C + (size_t)mrow*ldc + n0) = c0;
    *(float4*)(C + (size_t)mrow*ldc + n1) = c1;
  }
}

// ---------------------------------------------------------------------------
// Causal depthwise conv (k=4) + bias + SiLU: XI f32 -> U2 split pair.
// ---------------------------------------------------------------------------
__global__ __launch_bounds__(256)
void conv_silu_kernel(const float* __restrict__ xi, const float* __restrict__ cw,
                      const float* __restrict__ cb, unsigned short* __restrict__ u2)
{
  int idx = blockIdx.x*256 + threadIdx.x;
  int d = idx & (DINNER-1);
  int g = idx >> 11;
  int t0 = (g & 511) << 2;
  int b = g >> 9;
  float4 w4 = *(const float4*)(cw + d*4);
  float bias = cb[d];
  const float* base = xi + (size_t)b*SEQL*DINNER + d;
  float v[7];
  #pragma unroll
  for (int j=0;j<7;j++){
    int t = t0-3+j;
    v[j] = (t>=0) ? base[(size_t)t*DINNER] : 0.f;
  }
  unsigned short* outp = u2 + ((size_t)b*SEQL + t0)*4096 + d;
  #pragma unroll
  for (int j=0;j<4;j++){
    float y = fmaf(v[j+3], w4.w, fmaf(v[j+2], w4.z, fmaf(v[j+1], w4.y, fmaf(v[j], w4.x, bias))));
    float uv = siluf(y);
    unsigned short h,l;
    split_bf(uv, h, l);
    outp[(size_t)j*4096]        = h;
    outp[(size_t)j*4096 + 2048] = l;
  }
}

// ---------------------------------------------------------------------------
// Chunked selective scan, LDS-tiled, fully unrolled (unchanged from r9).
// ---------------------------------------------------------------------------
template<int PASS>
__global__ __launch_bounds__(256)
void scan_chunk(const unsigned short* __restrict__ u2, float* __restrict__ dty,
                const float* __restrict__ xdbl, const float* __restrict__ zb,
                const float* __restrict__ A_log, const float* __restrict__ Dp,
                float* __restrict__ hfin, float* __restrict__ sumdt)
{
  __shared__ __align__(16) float Tdt[TT][256];
  __shared__ __align__(16) float Tu [TT][256];
  __shared__ __align__(16) float Tz [TT][256];

  const int tid = threadIdx.x;
  const int idx = blockIdx.x*256 + tid;
  const int d = idx & (DINNER-1);
  const int g = idx >> 11;          // uniform per block
  const int cck = g & (NC-1);
  const int bb = g >> 5;
  const int wv = tid >> 6, ln = tid & 63;
  const int dbase = (blockIdx.x << 8) & (DINNER-1);

  float A2[16];
  {
    const float* al = A_log + (size_t)d*DSTATE;
    #pragma unroll
    for (int s=0;s<16;s++) A2[s] = -expf(al[s]) * 1.44269504f;
  }
  float h[16];
  if (PASS == 1){
    #pragma unroll
    for (int s=0;s<16;s++) h[s] = 0.f;
  } else {
    const float* hp = hfin + ((size_t)g*DINNER + d)*16;
    #pragma unroll
    for (int s=0;s<16;s+=4) *(float4*)&h[s] = *(const float4*)(hp + s);
  }
  const float Dv = (PASS==3) ? Dp[d] : 0.f;

  const size_t row0 = (size_t)bb*SEQL + (size_t)cck*TC;
  const float* pbc = xdbl + row0*96 + 64;

  float Bb[2][16], Cb[2][16];
#define LOAD_BC(buf, t) { const float4* p4 = (const float4*)(pbc + (size_t)(t)*96); \
    *(float4*)&Bb[buf][0]=p4[0]; *(float4*)&Bb[buf][4]=p4[1]; \
    *(float4*)&Bb[buf][8]=p4[2]; *(float4*)&Bb[buf][12]=p4[3]; \
    if (PASS==3){ \
    *(float4*)&Cb[buf][0]=p4[4]; *(float4*)&Cb[buf][4]=p4[5]; \
    *(float4*)&Cb[buf][8]=p4[6]; *(float4*)&Cb[buf][12]=p4[7]; } }

  LOAD_BC(0, 0);
  float sdt = 0.f;

  for (int t0 = 0; t0 < TC; t0 += TT){
    #pragma unroll
    for (int q=0;q<2;q++){
      int r = q*4 + wv;
      size_t rowi = row0 + t0 + r;
      gld16(dty + rowi*2048 + dbase + ln*4, &Tdt[r][0]);
      const unsigned short* us = u2 + rowi*4096 +
          ((ln < 32) ? (dbase + ln*8) : (2048 + dbase + (ln-32)*8));
      gld16(us, &Tu[r][0]);
      if (PASS==3) gld16(zb + rowi*2048 + dbase + ln*4, &Tz[r][0]);
    }
    __syncthreads();

    #pragma unroll
    for (int tt=0; tt<TT; tt++){
      const int t = t0 + tt;
      const int cur = tt & 1, nxt = cur^1;   // compile-time
      float dtc = Tdt[tt][tid];
      const unsigned short* tur = (const unsigned short*)&Tu[tt][0];
      float uc = __uint_as_float((u32)tur[tid] << 16)
               + __uint_as_float((u32)tur[256+tid] << 16);
      float zc  = (PASS==3) ? Tz[tt][tid] : 0.f;
      if (t+1 < TC) LOAD_BC(nxt, t+1);
      if (PASS==1) sdt += dtc;
      float du = dtc*uc;
      float y = 0.f;
      #pragma unroll
      for (int s=0;s<16;s++){
        float dA = exp2f(dtc*A2[s]);
        h[s] = fmaf(dA, h[s], du*Bb[cur][s]);
        if (PASS==3) y = fmaf(h[s], Cb[cur][s], y);
      }
      if (PASS==3){
        y = fmaf(uc, Dv, y);
        float gv = y * siluf(zc);
        unsigned short gh, gl;
        split_bf(gv, gh, gl);
        Tdt[tt][tid] = __uint_as_float((u32)gh | ((u32)gl << 16));
      }
    }

    if (PASS==3){
      __syncthreads();
      #pragma unroll
      for (int q=0;q<2;q++){
        int r = q*4 + wv;
        size_t rowi = row0 + t0 + r;
        const u32* T = (const u32*)&Tdt[r][0];
        int o0 = ln*4;
        u32 vals[4];
        if (ln < 32){
          #pragma unroll
          for (int k=0;k<4;k++){
            int i2 = (o0+k)*2;
            vals[k] = (T[i2] & 0xFFFFu) | (T[i2+1] << 16);
          }
        } else {
          #pragma unroll
          for (int k=0;k<4;k++){
            int i2 = (o0+k-128)*2;
            vals[k] = (T[i2] >> 16) | (T[i2+1] & 0xFFFF0000u);
          }
        }
        *(float4*)(dty + rowi*2048 + dbase + o0) = *(const float4*)vals;
      }
    }
    __syncthreads();
  }
#undef LOAD_BC

  if (PASS==1){
    float* hp = hfin + ((size_t)g*DINNER + d)*16;
    #pragma unroll
    for (int s=0;s<16;s+=4) *(float4*)(hp + s) = *(const float4*)&h[s];
    sumdt[(size_t)g*DINNER + d] = sdt;
  }
}

// ---------------------------------------------------------------------------
// Propagate chunk-initial states: in-place hfin[c] := H_init(c).
// ---------------------------------------------------------------------------
__global__ __launch_bounds__(256)
void scan_prop(const float* __restrict__ A_log, float* __restrict__ hfin,
               const float* __restrict__ sumdt)
{
  int idx = blockIdx.x*256 + threadIdx.x;
  int s = idx & 15;
  int d = (idx >> 4) & (DINNER-1);
  int b = idx >> 15;
  float A2 = -expf(A_log[(size_t)d*DSTATE + s]) * 1.44269504f;
  float H = 0.f;
  size_t hbase = ((size_t)b*NC*DINNER + d)*16 + s;
  size_t sbase = (size_t)b*NC*DINNER + d;
  for (int c=0;c<NC;c++){
    float P   = exp2f(A2 * sumdt[sbase + (size_t)c*DINNER]);
    float tmp = hfin[hbase + (size_t)c*DINNER*16];
    hfin[hbase + (size_t)c*DINNER*16] = H;
    H = fmaf(P, H, tmp);
  }
}

// ---------------------------------------------------------------------------
// Launcher.  Fixed (51.9 MB): INW2 33.55 + OUTWG 16.78 + XPW2 1.57.
// Per batch (58.72 MB): SH 8.39 (aliases XD/HF/SD) + XI 16.78 + ZB 16.78 +
// U2 16.78.  NB=4 -> 286.8 MB (< 305.1 known-good).
// ---------------------------------------------------------------------------
extern "C" void kernel_launch(void* const* d_in, const int* in_sizes, int n_in,
                              void* d_out, int out_size, void* d_ws, size_t ws_size,
                              hipStream_t stream)
{
  const float* x    = (const float*)d_in[0];
  const float* in_w = (const float*)d_in[1];
  const float* cw   = (const float*)d_in[2];
  const float* cb   = (const float*)d_in[3];
  const float* xpw  = (const float*)d_in[4];
  const float* dtw  = (const float*)d_in[5];
  const float* dtb  = (const float*)d_in[6];
  const float* A_log= (const float*)d_in[7];
  const float* Dp   = (const float*)d_in[8];
  const float* ow   = (const float*)d_in[9];
  const float* nw   = (const float*)d_in[10];
  const float* nb   = (const float*)d_in[11];
  float* outF = (float*)d_out;

  const size_t fixedB = 33554432ULL + 16777216ULL + 1572864ULL;  // 51,904,512
  const size_t perB   = 58720256ULL;
  int NB = 4;
  while (NB > 1 && fixedB + (size_t)NB*perB > ws_size) NB >>= 1;
  const int Mc = NB * SEQL;
  const int nchunk = SEQB / NB;

  unsigned short* INW2  = (unsigned short*)d_ws;                 // [2][4096][2048]
  unsigned short* OUTWG = INW2 + (size_t)2*4096*2048;            // [2][1024][4096]
  unsigned short* XPW2  = OUTWG + (size_t)2*1024*4096;           // [2][96][4096]
  char* dyn = (char*)(XPW2 + (size_t)2*96*4096);

  unsigned short* SH = (unsigned short*)dyn;                     // Mc*2048 ushort
  float* XD = (float*)dyn;                                       // Mc*96  (alias SH)
  float* HF = (float*)(dyn + (size_t)Mc*384);                    // Mc*512 (alias SH)
  float* SD = (float*)(dyn + (size_t)Mc*2432);                   // Mc*32  (alias SH)
  float* XI = (float*)(dyn + (size_t)Mc*4096);                   // Mc*2048 f32
  float* ZB = XI + (size_t)Mc*2048;                              // Mc*2048
  unsigned short* U2 = (unsigned short*)(ZB + (size_t)Mc*2048);  // Mc*4096 ushort

  // Weight pre-splits
  wsplit2<<<8192, 256, 0, stream>>>(in_w, INW2, 1024, 8);
  wsplit2<<<384,  256, 0, stream>>>(xpw,  XPW2, 2048, 9);
  wsplit_og<<<4096, 256, 0, stream>>>(ow, OUTWG);

  for (int c = 0; c < nchunk; ++c){
    const size_t rowoff = (size_t)c * Mc;
    const float* xrows = x + rowoff * DMODEL;
    float* X1 = outF + rowoff * DMODEL;     // layer-0 out / final out rows

    for (int l = 0; l < 2; ++l){
      const float* Al = A_log + (size_t)l*DINNER*DSTATE;

      // 1. LayerNorm (+ residual for layer 1) -> SH pair
      ln_split2<<<Mc, 256, 0, stream>>>(
          (l==0) ? xrows : X1, (l==0) ? nullptr : xrows,
          nw + (size_t)l*DMODEL, nb + (size_t)l*DMODEL, SH);

      // 2. in_proj fused xi|z: cols<2048 -> XI, cols>=2048 -> ZB
      mgemm_in<<<dim3(32, Mc/128), 256, 0, stream>>>(
          SH, INW2 + (size_t)l*4096*2048, XI, ZB);

      // 3. causal conv + bias + SiLU: XI -> U2 (split pair)
      conv_silu_kernel<<<NB*4096, 256, 0, stream>>>(
          XI, cw + (size_t)l*DINNER*4, cb + (size_t)l*DINNER, U2);

      // 4. x_proj (pure pair GEMM) -> XD
      xproj_pair<<<Mc/32, 256, 0, stream>>>(
          U2, XPW2 + (size_t)l*96*4096, XD);

      // 5. dt_proj + bias + softplus -> XI (xi dead after conv)
      gemm_dt<<<dim3(16, Mc/128), 256, 0, stream>>>(
          XD, 96, dtw + (size_t)l*DINNER*64, 64, XI, DINNER, 64,
          dtb + (size_t)l*DINNER);

      // 6. chunked scan; pass 3 writes grouped-plane gy over XI
      scan_chunk<1><<<NB*NC*8, 256, 0, stream>>>(
          U2, XI, XD, ZB, Al, Dp + (size_t)l*DINNER, HF, SD);
      scan_prop<<<NB*128, 256, 0, stream>>>(Al, HF, SD);
      scan_chunk<3><<<NB*NC*8, 256, 0, stream>>>(
          U2, XI, XD, ZB, Al, Dp + (size_t)l*DINNER, HF, SD);

      // 7. out_proj: grouped-A x grouped-B, 3 virtual passes -> X1 rows
      mgemm_out3<<<dim3(8, Mc/128), 256, 0, stream>>>(
          (const unsigned short*)XI, OUTWG + (size_t)l*1024*4096, X1);
    }
  }
}